// Round 13
// baseline (2168.404 us; speedup 1.0000x reference)
//
#include <hip/hip_runtime.h>
#include <hip/hip_bf16.h>

// Spiking transformer block (Spikformer SSA) on MI355X.
// Layout: [channel][m], m = (b*196+n)*4 + t (time innermost).
//
// CORRECTNESS CONTRACT (r11/r12 PASSED, absmax 0.0 bitwise):
//  - v branch: numpy SSE2-SOP einsum flavor — 4 stripe accumulators (lane=c&3),
//    c ascending, separate __fmul_rn/__fadd_rn, reduce (s0+s2)+(s1+s3),
//    unfused __f*_rn BN/LIF.  - out0 branches: in-order ascending-k fp32 FMA
//    chain per element, zero-init.  - elementwise kernels byte-identical.
// Retiling is bitwise-safe; MFMA / k-splitting / flavor changes are NOT.
// r12 lesson: acc[8][8] spilled (VGPR=52 reported) -> this round 8x4 microtile
// + __launch_bounds__(256,2) to keep accumulators register-resident.

#define Cv 384
#define Nv 196
#define Mv 25088        // 128*196 columns
#define HIDv 1536
#define Bv 32
#define Zv 6272         // z = b*196+n
#define TBv 128
#define CHUNK 12544     // Mv/2
#define UC 3136         // per-chunk u

// ---- transpose: xp[c*Mv + (b*196+n)*4 + t] = x[((t*32+b)*384+c)*196+n] ----
__global__ __launch_bounds__(256) void k_transpose_in(const float* __restrict__ x,
                                                      float* __restrict__ xp)
{
    int idx = blockIdx.x * 256 + threadIdx.x;
    int c   = idx / Mv;
    int rem = idx - c * Mv;
    int z = rem >> 2, t = rem & 3;
    int b = z / Nv, n = z - b * Nv;
    xp[idx] = x[((size_t)(t * Bv + b) * Cv + c) * Nv + n];
}

// ---- fp32 GEMM, 128o x 64m tile, BK=16, 8x4 microtile, in-order FMA chains -
// Bitwise == r4 k_gemm per element: acc = fmaf(W[o][k], X[k][m], acc), k asc.
__global__ __launch_bounds__(256, 2) void k_gemm2(const float* __restrict__ W,
                                                  const float* __restrict__ X,
                                                  float* __restrict__ Y,
                                                  int K, int ldx, int ldy,
                                                  const float* __restrict__ bias,
                                                  int cb)
{
    __shared__ float sW[16][128];
    __shared__ float sX[16][64];
    int ym0 = blockIdx.x * 64;
    int m0  = cb + ym0;
    int o0  = blockIdx.y * 128;
    int tid = threadIdx.x;
    int wo = tid & 127, wh = tid >> 7;        // W stage: o row, k-half (8 k's)
    int xr = tid >> 4,  xc = (tid & 15) * 4;  // X stage: k row, float4 col
    int to = tid >> 4,  tm = tid & 15;        // microtile coords

    const float* Wp = W + (size_t)(o0 + wo) * K + wh * 8;
    const float* Xp = X + (size_t)xr * ldx + m0 + xc;

    float acc[8][4];
    #pragma unroll
    for (int i = 0; i < 8; ++i)
        #pragma unroll
        for (int j = 0; j < 4; ++j) acc[i][j] = 0.0f;

    for (int k0 = 0; k0 < K; k0 += 16) {
        float4 wa = *(const float4*)(Wp + k0);
        float4 wb = *(const float4*)(Wp + k0 + 4);
        float4 x4 = *(const float4*)(Xp + (size_t)k0 * ldx);
        __syncthreads();
        sW[wh*8+0][wo] = wa.x;
        sW[wh*8+1][wo] = wa.y;
        sW[wh*8+2][wo] = wa.z;
        sW[wh*8+3][wo] = wa.w;
        sW[wh*8+4][wo] = wb.x;
        sW[wh*8+5][wo] = wb.y;
        sW[wh*8+6][wo] = wb.z;
        sW[wh*8+7][wo] = wb.w;
        *(float4*)&sX[xr][xc] = x4;
        __syncthreads();
        #pragma unroll
        for (int kk = 0; kk < 16; ++kk) {
            float4 a0 = *(const float4*)&sW[kk][to*4];
            float4 a1 = *(const float4*)&sW[kk][64 + to*4];
            float4 bb = *(const float4*)&sX[kk][tm*4];
            float av[8] = {a0.x,a0.y,a0.z,a0.w,a1.x,a1.y,a1.z,a1.w};
            float bv[4] = {bb.x,bb.y,bb.z,bb.w};
            #pragma unroll
            for (int i = 0; i < 8; ++i)
                #pragma unroll
                for (int j = 0; j < 4; ++j)
                    acc[i][j] = fmaf(av[i], bv[j], acc[i][j]);
        }
    }
    #pragma unroll
    for (int i = 0; i < 8; ++i) {
        int oi = (i < 4) ? (to*4 + i) : (64 + to*4 + i - 4);
        int o  = o0 + oi;
        float bb = bias ? bias[o] : 0.0f;
        float4 r;
        r.x = acc[i][0] + bb; r.y = acc[i][1] + bb;
        r.z = acc[i][2] + bb; r.w = acc[i][3] + bb;
        *(float4*)&Y[(size_t)o * ldy + ym0 + tm*4] = r;
    }
}

// ---- V branch: SSE2-SOP GEMM, 64x64 tile, 4o x 1site microtile -------------
// Bitwise == r11 k_gemm_vsse per element: 4 stripe chains (c asc, mul+add
// separate), reduce (s0+s2)+(s1+s3), unfused __f*_rn BN/LIF epilogue.
__global__ __launch_bounds__(256, 2) void k_vsse2(const float* __restrict__ W,
                                                  const float* __restrict__ X,
                                                  const float* __restrict__ bnp,
                                                  __hip_bfloat16* __restrict__ Y)
{
    __shared__ float sW[32][68];    // [kk][o], pad 68 keeps 16B align + 2-way
    __shared__ float sX[32][64];
    int m0 = blockIdx.x * 64;
    int o0 = blockIdx.y * 64;
    int tid = threadIdx.x;
    int to = tid >> 4, tm = tid & 15;

    float acc[4][4][4];     // [stripe][o'][e]
    #pragma unroll
    for (int s = 0; s < 4; ++s)
        #pragma unroll
        for (int op = 0; op < 4; ++op)
            #pragma unroll
            for (int e = 0; e < 4; ++e) acc[s][op][e] = 0.0f;

    int wq_o = tid >> 3, wq_c = tid & 7;      // W stage: 64 o x 8 float4-cols
    int xs_r = tid >> 3, xs_c = (tid & 7) * 8; // X stage: 32 rows x 2 float4

    for (int blk = 0; blk < 12; ++blk) {
        int k0 = blk * 32;
        __syncthreads();
        {   // stage W: sW[kk][o] = W[o0+o][k0+kk]
            float4 w4 = *(const float4*)(W + (size_t)(o0 + wq_o) * Cv + k0 + wq_c*4);
            sW[wq_c*4+0][wq_o] = w4.x;
            sW[wq_c*4+1][wq_o] = w4.y;
            sW[wq_c*4+2][wq_o] = w4.z;
            sW[wq_c*4+3][wq_o] = w4.w;
            float4 w5 = *(const float4*)(W + (size_t)(o0 + 32 + wq_o) * Cv + k0 + wq_c*4);
            sW[wq_c*4+0][32 + wq_o] = w5.x;
            sW[wq_c*4+1][32 + wq_o] = w5.y;
            sW[wq_c*4+2][32 + wq_o] = w5.z;
            sW[wq_c*4+3][32 + wq_o] = w5.w;
        }
        {   // stage X: sX[kk][m'] = X[k0+kk][m0+m']
            const float* Xp = X + (size_t)(k0 + xs_r) * Mv + m0 + xs_c;
            *(float4*)&sX[xs_r][xs_c]     = *(const float4*)(Xp);
            *(float4*)&sX[xs_r][xs_c + 4] = *(const float4*)(Xp + 4);
        }
        __syncthreads();
        #pragma unroll
        for (int j = 0; j < 8; ++j) {
            #pragma unroll
            for (int s = 0; s < 4; ++s) {
                int kk = j * 4 + s;             // c = k0 + j*4 + s  (stripe c&3)
                float4 w4 = *(const float4*)&sW[kk][to*4];
                float4 x4 = *(const float4*)&sX[kk][tm*4];
                float wv[4] = {w4.x, w4.y, w4.z, w4.w};
                float xv[4] = {x4.x, x4.y, x4.z, x4.w};
                #pragma unroll
                for (int op = 0; op < 4; ++op)
                    #pragma unroll
                    for (int e = 0; e < 4; ++e)
                        acc[s][op][e] = __fadd_rn(acc[s][op][e],
                                                  __fmul_rn(wv[op], xv[e]));
            }
        }
    }

    #pragma unroll
    for (int op = 0; op < 4; ++op) {
        int o = o0 + to*4 + op;
        float inv = __fdiv_rn(1.0f, __fsqrt_rn(__fadd_rn(bnp[3*Cv + o], 1e-5f)));
        float sc  = __fmul_rn(bnp[o], inv);
        float mu  = bnp[2*Cv + o];
        float be  = bnp[Cv + o];
        float mem = 0.0f;
        ushort4 pk;
        unsigned short* pks = (unsigned short*)&pk;
        #pragma unroll
        for (int e = 0; e < 4; ++e) {
            float tot = __fadd_rn(__fadd_rn(acc[0][op][e], acc[2][op][e]),
                                  __fadd_rn(acc[1][op][e], acc[3][op][e]));
            float bn = __fadd_rn(__fmul_rn(__fsub_rn(tot, mu), sc), be);
            mem = __fadd_rn(mem, __fmul_rn(__fsub_rn(bn, mem), 0.5f));
            int s = (mem > 1.0f);
            mem = s ? 0.0f : mem;
            pks[e] = s ? 0x3F80 : 0;
        }
        *(ushort4*)((unsigned short*)Y + (size_t)o * Mv + m0 + tm * 4) = pk;
    }
}

// ---- BN + LIF(thr=1) -> bf16 spikes (r4 flavor; q/k branches) --------------
__global__ __launch_bounds__(256) void k_bnlif_spike(const float* __restrict__ y,
                                                     const float* __restrict__ bnp,
                                                     __hip_bfloat16* __restrict__ sp)
{
    int idx = blockIdx.x * 256 + threadIdx.x;
    int c = idx / Zv;
    float gamma = bnp[c], beta = bnp[Cv+c], mean = bnp[2*Cv+c], var = bnp[3*Cv+c];
    float scale = gamma / sqrtf(var + 1e-5f);
    size_t base = (size_t)idx * 4;
    float4 yv = *(const float4*)(y + base);
    float xi[4] = {yv.x, yv.y, yv.z, yv.w};
    ushort4 pk;
    unsigned short* pks = (unsigned short*)&pk;
    float mem = 0.f;
    #pragma unroll
    for (int t = 0; t < 4; ++t) {
        float xv = (xi[t] - mean) * scale + beta;
        mem = mem + (xv - mem) * 0.5f;
        float s = (mem > 1.0f) ? 1.0f : 0.0f;
        mem *= (1.0f - s);
        pks[t] = (s > 0.5f) ? 0x3F80 : 0;
    }
    *(ushort4*)((unsigned short*)sp + base) = pk;
}

// ---- attention per (h, tbl): popcount QK^T, exact fp32 PV ------------------
__global__ __launch_bounds__(256) void k_attn(const __hip_bfloat16* __restrict__ qs,
                                              const __hip_bfloat16* __restrict__ ks,
                                              const __hip_bfloat16* __restrict__ vs,
                                              float* __restrict__ o_chan,
                                              float* __restrict__ v_out)
{
    int h = blockIdx.x, tbl = blockIdx.y;
    int t = tbl >> 5, b = tbl & 31;
    int tid = threadIdx.x;
    __shared__ unsigned kmask[196];
    __shared__ float vf[196][36];
    size_t chb  = (size_t)h * 32 * Mv;
    size_t colb = (size_t)b * Nv * 4 + t;

    for (int e = tid; e < Nv * 32; e += 256) {
        int dd = e / Nv, n = e - dd * Nv;
        vf[n][dd] = __bfloat162float(vs[chb + (size_t)dd * Mv + colb + (size_t)n * 4]);
    }
    unsigned qm = 0;
    if (tid < Nv) {
        unsigned km = 0;
        #pragma unroll
        for (int dd = 0; dd < 32; ++dd) {
            size_t off = chb + (size_t)dd * Mv + colb + (size_t)tid * 4;
            km |= (__bfloat162float(ks[off]) > 0.5f ? 1u : 0u) << dd;
            qm |= (__bfloat162float(qs[off]) > 0.5f ? 1u : 0u) << dd;
        }
        kmask[tid] = km;
    }
    __syncthreads();
    for (int e = tid; e < Nv * 32; e += 256) {
        int n = e >> 5, dd = e & 31;
        v_out[((size_t)(tbl * 12 + h) * Nv + n) * 32 + dd] = vf[n][dd];
    }
    if (tid < Nv) {
        float acc[32] = {};
        for (int nk = 0; nk < Nv; ++nk) {
            float a = (float)__popc(qm & kmask[nk]) * 0.125f;   // exact
            #pragma unroll
            for (int dd = 0; dd < 32; ++dd) acc[dd] += a * vf[nk][dd];
        }
        #pragma unroll
        for (int dd = 0; dd < 32; ++dd)
            o_chan[chb + (size_t)dd * Mv + colb + (size_t)tid * 4] = acc[dd];
    }
}

// ---- attn LIF (thr=0.5): exact (dyadic grid) -------------------------------
__global__ __launch_bounds__(256) void k_attnlif(float* __restrict__ o)
{
    int idx = blockIdx.x * 256 + threadIdx.x;
    size_t base = (size_t)idx * 4;
    float4 v = *(const float4*)(o + base);
    float xi[4] = {v.x, v.y, v.z, v.w};
    float s4[4];
    float mem = 0.f;
    #pragma unroll
    for (int t = 0; t < 4; ++t) {
        mem = mem + (xi[t] - mem) * 0.5f;
        s4[t] = (mem > 0.5f) ? 1.0f : 0.0f;
        mem *= (1.0f - s4[t]);
    }
    float4 r; r.x = s4[0]; r.y = s4[1]; r.z = s4[2]; r.w = s4[3];
    *(float4*)(o + base) = r;
}

// ---- proj BN+LIF(thr=1): x1 += s and s_proj (bf16) -------------------------
__global__ __launch_bounds__(256) void k_resid(const float* __restrict__ p,
                                               const float* __restrict__ bnp,
                                               float* __restrict__ x1,
                                               __hip_bfloat16* __restrict__ s_proj)
{
    int idx = blockIdx.x * 256 + threadIdx.x;
    int c = idx / Zv;
    float gamma = bnp[c], beta = bnp[Cv+c], mean = bnp[2*Cv+c], var = bnp[3*Cv+c];
    float scale = gamma / sqrtf(var + 1e-5f);
    size_t base = (size_t)idx * 4;
    float4 pv = *(const float4*)(p + base);
    float xi[4] = {pv.x, pv.y, pv.z, pv.w};
    float4 xv = *(const float4*)(x1 + base);
    float xr[4] = {xv.x, xv.y, xv.z, xv.w};
    ushort4 pk;
    unsigned short* pks = (unsigned short*)&pk;
    float mem = 0.f;
    #pragma unroll
    for (int t = 0; t < 4; ++t) {
        float bnv = (xi[t] - mean) * scale + beta;
        mem = mem + (bnv - mem) * 0.5f;
        float s = (mem > 1.0f) ? 1.0f : 0.0f;
        mem *= (1.0f - s);
        xr[t] += s;
        pks[t] = (s > 0.5f) ? 0x3F80 : 0;
    }
    float4 r; r.x = xr[0]; r.y = xr[1]; r.z = xr[2]; r.w = xr[3];
    *(float4*)(x1 + base) = r;
    *(ushort4*)((unsigned short*)s_proj + base) = pk;
}

// ---- fc1 BN+LIF(thr=1) in place on chunk buffer [1536][12544] --------------
__global__ __launch_bounds__(256) void k_bnlif_h(float* __restrict__ hbuf,
                                                 const float* __restrict__ bnp)
{
    int idx = blockIdx.x * 256 + threadIdx.x;
    int o = idx / UC;
    float gamma = bnp[o], beta = bnp[HIDv+o], mean = bnp[2*HIDv+o], var = bnp[3*HIDv+o];
    float scale = gamma / sqrtf(var + 1e-5f);
    size_t base = (size_t)idx * 4;
    float4 hv = *(const float4*)(hbuf + base);
    float xi[4] = {hv.x, hv.y, hv.z, hv.w};
    float s4[4];
    float mem = 0.f;
    #pragma unroll
    for (int t = 0; t < 4; ++t) {
        float bnv = (xi[t] - mean) * scale + beta;
        mem = mem + (bnv - mem) * 0.5f;
        s4[t] = (mem > 1.0f) ? 1.0f : 0.0f;
        mem *= (1.0f - s4[t]);
    }
    float4 r; r.x = s4[0]; r.y = s4[1]; r.z = s4[2]; r.w = s4[3];
    *(float4*)(hbuf + base) = r;
}

// ---- fc2 BN+LIF + out = x(direct) + s_proj + s_fc2, FP32 -------------------
__global__ __launch_bounds__(256) void k_final(const float* __restrict__ h2,
                                               const float* __restrict__ bnp,
                                               const float* __restrict__ x,
                                               const __hip_bfloat16* __restrict__ s_proj,
                                               float* __restrict__ out,
                                               int b0)
{
    int idx = blockIdx.x * 256 + threadIdx.x;
    int c = idx / UC;
    int u = idx - c * UC;
    int bp = u / Nv, n = u - bp * Nv;
    int b = b0 + bp;
    float gamma = bnp[c], beta = bnp[Cv+c], mean = bnp[2*Cv+c], var = bnp[3*Cv+c];
    float scale = gamma / sqrtf(var + 1e-5f);
    float4 hv = *(const float4*)(h2 + (size_t)c * CHUNK + (size_t)u * 4);
    float xi[4] = {hv.x, hv.y, hv.z, hv.w};
    ushort4 sp4 = *(const ushort4*)((const unsigned short*)s_proj +
                                    (size_t)c * Mv + ((size_t)b * Nv + n) * 4);
    unsigned short* sps = (unsigned short*)&sp4;
    float mem = 0.f;
    #pragma unroll
    for (int t = 0; t < 4; ++t) {
        float bnv = (xi[t] - mean) * scale + beta;
        mem = mem + (bnv - mem) * 0.5f;
        float s = (mem > 1.0f) ? 1.0f : 0.0f;
        mem *= (1.0f - s);
        size_t oidx = ((size_t)(t * Bv + b) * Cv + c) * Nv + n;
        float sproj = sps[t] ? 1.0f : 0.0f;
        out[oidx] = x[oidx] + sproj + s;
    }
}

extern "C" void kernel_launch(void* const* d_in, const int* in_sizes, int n_in,
                              void* d_out, int out_size, void* d_ws, size_t ws_size,
                              hipStream_t stream)
{
    const float* x       = (const float*)d_in[0];
    const float* qkvp_w  = (const float*)d_in[1];
    const float* qkvp_bn = (const float*)d_in[2];
    const float* fc1_w   = (const float*)d_in[3];
    const float* fc1_b   = (const float*)d_in[4];
    const float* fc1_bn  = (const float*)d_in[5];
    const float* fc2_w   = (const float*)d_in[6];
    const float* fc2_b   = (const float*)d_in[7];
    const float* fc2_bn  = (const float*)d_in[8];

    float* out1 = (float*)d_out;                    // x_out fp32
    float* out2 = out1 + (size_t)TBv * Cv * Nv;     // v fp32

    float* wsf = (float*)d_ws;
    const size_t S = (size_t)Cv * Mv;
    if (ws_size < 4 * S * sizeof(float)) return;

    float* xp   = wsf;                                  // xp -> x1
    float* ybuf = wsf + S;                              // pre-BN y / attn o
    __hip_bfloat16* qs = (__hip_bfloat16*)(wsf + 2*S);
    __hip_bfloat16* ks = qs + S;
    __hip_bfloat16* vs = qs + 2*S;
    float* pbuf  = wsf + 2*S;                           // proj pre-BN (q/k dead)
    float* hbuf  = wsf + S;                             // fc1 out
    float* h2buf = wsf + 3*S;                           // fc2 out (vs dead)
    __hip_bfloat16* s_proj = (__hip_bfloat16*)(wsf + 3*S + S/2);

    k_transpose_in<<<37632, 256, 0, stream>>>(x, xp);

    // q, k: in-order FMA GEMM (retiled, bitwise == r4) + proven BN/LIF
    for (int br = 0; br < 2; ++br) {
        k_gemm2<<<dim3(392, 3), 256, 0, stream>>>(qkvp_w + (size_t)br*Cv*Cv, xp, ybuf,
                                                  Cv, Mv, Mv, nullptr, 0);
        __hip_bfloat16* sp = (br == 0) ? qs : ks;
        k_bnlif_spike<<<9408, 256, 0, stream>>>(ybuf, qkvp_bn + (size_t)br*4*Cv, sp);
    }
    // v: SSE2-SOP flavor (retiled, bitwise == r11)
    k_vsse2<<<dim3(392, 6), 256, 0, stream>>>(qkvp_w + (size_t)2*Cv*Cv, xp,
                                              qkvp_bn + (size_t)2*4*Cv, vs);

    k_attn<<<dim3(12, 128), 256, 0, stream>>>(qs, ks, vs, ybuf, out2);
    k_attnlif<<<9408, 256, 0, stream>>>(ybuf);

    k_gemm2<<<dim3(392, 3), 256, 0, stream>>>(qkvp_w + (size_t)3*Cv*Cv, ybuf, pbuf,
                                              Cv, Mv, Mv, nullptr, 0);
    k_resid<<<9408, 256, 0, stream>>>(pbuf, qkvp_bn + (size_t)3*4*Cv, xp, s_proj);

    for (int ch = 0; ch < 2; ++ch) {
        k_gemm2<<<dim3(196, 12), 256, 0, stream>>>(fc1_w, xp, hbuf,
                                                   Cv, Mv, CHUNK, fc1_b, ch * CHUNK);
        k_bnlif_h<<<18816, 256, 0, stream>>>(hbuf, fc1_bn);
        k_gemm2<<<dim3(196, 3), 256, 0, stream>>>(fc2_w, hbuf, h2buf,
                                                  HIDv, CHUNK, CHUNK, fc2_b, 0);
        k_final<<<4704, 256, 0, stream>>>(h2buf, fc2_bn, x, s_proj, out1, ch * 16);
    }
}

// Round 14
// 1466.954 us; speedup vs baseline: 1.4782x; 1.4782x over previous
//
#include <hip/hip_runtime.h>
#include <hip/hip_bf16.h>

// Spiking transformer block (Spikformer SSA) on MI355X.
// Layout: [channel][m], m = (b*196+n)*4 + t (time innermost).
//
// CORRECTNESS CONTRACT (r11/r12/r13 PASSED, absmax 0.0 bitwise):
//  - v branch: numpy SSE2-SOP einsum flavor — 4 stripe accumulators (lane=c&3),
//    c ascending, separate __fmul_rn/__fadd_rn, reduce (s0+s2)+(s1+s3),
//    unfused __f*_rn BN/LIF.  - out0 branches: in-order ascending-k fp32 FMA
//    chain per element, zero-init.  - elementwise kernels byte-identical.
// Retiling is bitwise-safe; MFMA / k-splitting / flavor changes are NOT.
// r13 lesson: __launch_bounds__(256,2) on vsse2 capped the unified VGPR/AGPR
// file -> scratch spill (2.1GB writes/dispatch, 847us). NO min-waves hints on
// accumulator-heavy kernels; the allocator parks accs in AGPRs when uncapped.

#define Cv 384
#define Nv 196
#define Mv 25088        // 128*196 columns
#define HIDv 1536
#define Bv 32
#define Zv 6272         // z = b*196+n
#define TBv 128
#define CHUNK 12544     // Mv/2
#define UC 3136         // per-chunk u

// ---- transpose: xp[c*Mv + (b*196+n)*4 + t] = x[((t*32+b)*384+c)*196+n] ----
__global__ __launch_bounds__(256) void k_transpose_in(const float* __restrict__ x,
                                                      float* __restrict__ xp)
{
    int idx = blockIdx.x * 256 + threadIdx.x;
    int c   = idx / Mv;
    int rem = idx - c * Mv;
    int z = rem >> 2, t = rem & 3;
    int b = z / Nv, n = z - b * Nv;
    xp[idx] = x[((size_t)(t * Bv + b) * Cv + c) * Nv + n];
}

// ---- fp32 GEMM, 128o x 64m tile, BK=16, 8x4 microtile, in-order FMA chains -
// Bitwise == r4 k_gemm per element: acc = fmaf(W[o][k], X[k][m], acc), k asc.
__global__ __launch_bounds__(256) void k_gemm2(const float* __restrict__ W,
                                               const float* __restrict__ X,
                                               float* __restrict__ Y,
                                               int K, int ldx, int ldy,
                                               const float* __restrict__ bias,
                                               int cb)
{
    __shared__ float sW[16][128];
    __shared__ float sX[16][64];
    int ym0 = blockIdx.x * 64;
    int m0  = cb + ym0;
    int o0  = blockIdx.y * 128;
    int tid = threadIdx.x;
    int wo = tid & 127, wh = tid >> 7;        // W stage: o row, k-half (8 k's)
    int xr = tid >> 4,  xc = (tid & 15) * 4;  // X stage: k row, float4 col
    int to = tid >> 4,  tm = tid & 15;        // microtile coords

    const float* Wp = W + (size_t)(o0 + wo) * K + wh * 8;
    const float* Xp = X + (size_t)xr * ldx + m0 + xc;

    float acc[8][4];
    #pragma unroll
    for (int i = 0; i < 8; ++i)
        #pragma unroll
        for (int j = 0; j < 4; ++j) acc[i][j] = 0.0f;

    for (int k0 = 0; k0 < K; k0 += 16) {
        float4 wa = *(const float4*)(Wp + k0);
        float4 wb = *(const float4*)(Wp + k0 + 4);
        float4 x4 = *(const float4*)(Xp + (size_t)k0 * ldx);
        __syncthreads();
        sW[wh*8+0][wo] = wa.x;
        sW[wh*8+1][wo] = wa.y;
        sW[wh*8+2][wo] = wa.z;
        sW[wh*8+3][wo] = wa.w;
        sW[wh*8+4][wo] = wb.x;
        sW[wh*8+5][wo] = wb.y;
        sW[wh*8+6][wo] = wb.z;
        sW[wh*8+7][wo] = wb.w;
        *(float4*)&sX[xr][xc] = x4;
        __syncthreads();
        #pragma unroll
        for (int kk = 0; kk < 16; ++kk) {
            float4 a0 = *(const float4*)&sW[kk][to*4];
            float4 a1 = *(const float4*)&sW[kk][64 + to*4];
            float4 bb = *(const float4*)&sX[kk][tm*4];
            float av[8] = {a0.x,a0.y,a0.z,a0.w,a1.x,a1.y,a1.z,a1.w};
            float bv[4] = {bb.x,bb.y,bb.z,bb.w};
            #pragma unroll
            for (int i = 0; i < 8; ++i)
                #pragma unroll
                for (int j = 0; j < 4; ++j)
                    acc[i][j] = fmaf(av[i], bv[j], acc[i][j]);
        }
    }
    #pragma unroll
    for (int i = 0; i < 8; ++i) {
        int oi = (i < 4) ? (to*4 + i) : (64 + to*4 + i - 4);
        int o  = o0 + oi;
        float bb = bias ? bias[o] : 0.0f;
        float4 r;
        r.x = acc[i][0] + bb; r.y = acc[i][1] + bb;
        r.z = acc[i][2] + bb; r.w = acc[i][3] + bb;
        *(float4*)&Y[(size_t)o * ldy + ym0 + tm*4] = r;
    }
}

// ---- V branch: SSE2-SOP GEMM, 64x64 tile, 4o x 1site microtile -------------
// Bitwise == r11 k_gemm_vsse per element. EXACT r12 version (no occupancy
// hint -> accumulators live in AGPRs, no spill).
__global__ __launch_bounds__(256) void k_vsse2(const float* __restrict__ W,
                                               const float* __restrict__ X,
                                               const float* __restrict__ bnp,
                                               __hip_bfloat16* __restrict__ Y)
{
    __shared__ float sW[32][68];    // [kk][o], pad 68 keeps 16B align + 2-way
    __shared__ float sX[32][64];
    int m0 = blockIdx.x * 64;
    int o0 = blockIdx.y * 64;
    int tid = threadIdx.x;
    int to = tid >> 4, tm = tid & 15;

    float acc[4][4][4];     // [stripe][o'][e]
    #pragma unroll
    for (int s = 0; s < 4; ++s)
        #pragma unroll
        for (int op = 0; op < 4; ++op)
            #pragma unroll
            for (int e = 0; e < 4; ++e) acc[s][op][e] = 0.0f;

    int wq_o = tid >> 3, wq_c = tid & 7;      // W stage: 64 o x 8 float4-cols
    int xs_r = tid >> 3, xs_c = (tid & 7) * 8; // X stage: 32 rows x 2 float4

    for (int blk = 0; blk < 12; ++blk) {
        int k0 = blk * 32;
        __syncthreads();
        {   // stage W: sW[kk][o] = W[o0+o][k0+kk]
            float4 w4 = *(const float4*)(W + (size_t)(o0 + wq_o) * Cv + k0 + wq_c*4);
            sW[wq_c*4+0][wq_o] = w4.x;
            sW[wq_c*4+1][wq_o] = w4.y;
            sW[wq_c*4+2][wq_o] = w4.z;
            sW[wq_c*4+3][wq_o] = w4.w;
            float4 w5 = *(const float4*)(W + (size_t)(o0 + 32 + wq_o) * Cv + k0 + wq_c*4);
            sW[wq_c*4+0][32 + wq_o] = w5.x;
            sW[wq_c*4+1][32 + wq_o] = w5.y;
            sW[wq_c*4+2][32 + wq_o] = w5.z;
            sW[wq_c*4+3][32 + wq_o] = w5.w;
        }
        {   // stage X: sX[kk][m'] = X[k0+kk][m0+m']
            const float* Xp = X + (size_t)(k0 + xs_r) * Mv + m0 + xs_c;
            *(float4*)&sX[xs_r][xs_c]     = *(const float4*)(Xp);
            *(float4*)&sX[xs_r][xs_c + 4] = *(const float4*)(Xp + 4);
        }
        __syncthreads();
        #pragma unroll
        for (int j = 0; j < 8; ++j) {
            #pragma unroll
            for (int s = 0; s < 4; ++s) {
                int kk = j * 4 + s;             // c = k0 + j*4 + s  (stripe c&3)
                float4 w4 = *(const float4*)&sW[kk][to*4];
                float4 x4 = *(const float4*)&sX[kk][tm*4];
                float wv[4] = {w4.x, w4.y, w4.z, w4.w};
                float xv[4] = {x4.x, x4.y, x4.z, x4.w};
                #pragma unroll
                for (int op = 0; op < 4; ++op)
                    #pragma unroll
                    for (int e = 0; e < 4; ++e)
                        acc[s][op][e] = __fadd_rn(acc[s][op][e],
                                                  __fmul_rn(wv[op], xv[e]));
            }
        }
    }

    #pragma unroll
    for (int op = 0; op < 4; ++op) {
        int o = o0 + to*4 + op;
        float inv = __fdiv_rn(1.0f, __fsqrt_rn(__fadd_rn(bnp[3*Cv + o], 1e-5f)));
        float sc  = __fmul_rn(bnp[o], inv);
        float mu  = bnp[2*Cv + o];
        float be  = bnp[Cv + o];
        float mem = 0.0f;
        ushort4 pk;
        unsigned short* pks = (unsigned short*)&pk;
        #pragma unroll
        for (int e = 0; e < 4; ++e) {
            float tot = __fadd_rn(__fadd_rn(acc[0][op][e], acc[2][op][e]),
                                  __fadd_rn(acc[1][op][e], acc[3][op][e]));
            float bn = __fadd_rn(__fmul_rn(__fsub_rn(tot, mu), sc), be);
            mem = __fadd_rn(mem, __fmul_rn(__fsub_rn(bn, mem), 0.5f));
            int s = (mem > 1.0f);
            mem = s ? 0.0f : mem;
            pks[e] = s ? 0x3F80 : 0;
        }
        *(ushort4*)((unsigned short*)Y + (size_t)o * Mv + m0 + tm * 4) = pk;
    }
}

// ---- BN + LIF(thr=1) -> bf16 spikes (r4 flavor; q/k branches) --------------
__global__ __launch_bounds__(256) void k_bnlif_spike(const float* __restrict__ y,
                                                     const float* __restrict__ bnp,
                                                     __hip_bfloat16* __restrict__ sp)
{
    int idx = blockIdx.x * 256 + threadIdx.x;
    int c = idx / Zv;
    float gamma = bnp[c], beta = bnp[Cv+c], mean = bnp[2*Cv+c], var = bnp[3*Cv+c];
    float scale = gamma / sqrtf(var + 1e-5f);
    size_t base = (size_t)idx * 4;
    float4 yv = *(const float4*)(y + base);
    float xi[4] = {yv.x, yv.y, yv.z, yv.w};
    ushort4 pk;
    unsigned short* pks = (unsigned short*)&pk;
    float mem = 0.f;
    #pragma unroll
    for (int t = 0; t < 4; ++t) {
        float xv = (xi[t] - mean) * scale + beta;
        mem = mem + (xv - mem) * 0.5f;
        float s = (mem > 1.0f) ? 1.0f : 0.0f;
        mem *= (1.0f - s);
        pks[t] = (s > 0.5f) ? 0x3F80 : 0;
    }
    *(ushort4*)((unsigned short*)sp + base) = pk;
}

// ---- attention per (h, tbl): popcount QK^T, exact fp32 PV ------------------
__global__ __launch_bounds__(256) void k_attn(const __hip_bfloat16* __restrict__ qs,
                                              const __hip_bfloat16* __restrict__ ks,
                                              const __hip_bfloat16* __restrict__ vs,
                                              float* __restrict__ o_chan,
                                              float* __restrict__ v_out)
{
    int h = blockIdx.x, tbl = blockIdx.y;
    int t = tbl >> 5, b = tbl & 31;
    int tid = threadIdx.x;
    __shared__ unsigned kmask[196];
    __shared__ float vf[196][36];
    size_t chb  = (size_t)h * 32 * Mv;
    size_t colb = (size_t)b * Nv * 4 + t;

    for (int e = tid; e < Nv * 32; e += 256) {
        int dd = e / Nv, n = e - dd * Nv;
        vf[n][dd] = __bfloat162float(vs[chb + (size_t)dd * Mv + colb + (size_t)n * 4]);
    }
    unsigned qm = 0;
    if (tid < Nv) {
        unsigned km = 0;
        #pragma unroll
        for (int dd = 0; dd < 32; ++dd) {
            size_t off = chb + (size_t)dd * Mv + colb + (size_t)tid * 4;
            km |= (__bfloat162float(ks[off]) > 0.5f ? 1u : 0u) << dd;
            qm |= (__bfloat162float(qs[off]) > 0.5f ? 1u : 0u) << dd;
        }
        kmask[tid] = km;
    }
    __syncthreads();
    for (int e = tid; e < Nv * 32; e += 256) {
        int n = e >> 5, dd = e & 31;
        v_out[((size_t)(tbl * 12 + h) * Nv + n) * 32 + dd] = vf[n][dd];
    }
    if (tid < Nv) {
        float acc[32] = {};
        for (int nk = 0; nk < Nv; ++nk) {
            float a = (float)__popc(qm & kmask[nk]) * 0.125f;   // exact
            #pragma unroll
            for (int dd = 0; dd < 32; ++dd) acc[dd] += a * vf[nk][dd];
        }
        #pragma unroll
        for (int dd = 0; dd < 32; ++dd)
            o_chan[chb + (size_t)dd * Mv + colb + (size_t)tid * 4] = acc[dd];
    }
}

// ---- attn LIF (thr=0.5): exact (dyadic grid) -------------------------------
__global__ __launch_bounds__(256) void k_attnlif(float* __restrict__ o)
{
    int idx = blockIdx.x * 256 + threadIdx.x;
    size_t base = (size_t)idx * 4;
    float4 v = *(const float4*)(o + base);
    float xi[4] = {v.x, v.y, v.z, v.w};
    float s4[4];
    float mem = 0.f;
    #pragma unroll
    for (int t = 0; t < 4; ++t) {
        mem = mem + (xi[t] - mem) * 0.5f;
        s4[t] = (mem > 0.5f) ? 1.0f : 0.0f;
        mem *= (1.0f - s4[t]);
    }
    float4 r; r.x = s4[0]; r.y = s4[1]; r.z = s4[2]; r.w = s4[3];
    *(float4*)(o + base) = r;
}

// ---- proj BN+LIF(thr=1): x1 += s and s_proj (bf16) -------------------------
__global__ __launch_bounds__(256) void k_resid(const float* __restrict__ p,
                                               const float* __restrict__ bnp,
                                               float* __restrict__ x1,
                                               __hip_bfloat16* __restrict__ s_proj)
{
    int idx = blockIdx.x * 256 + threadIdx.x;
    int c = idx / Zv;
    float gamma = bnp[c], beta = bnp[Cv+c], mean = bnp[2*Cv+c], var = bnp[3*Cv+c];
    float scale = gamma / sqrtf(var + 1e-5f);
    size_t base = (size_t)idx * 4;
    float4 pv = *(const float4*)(p + base);
    float xi[4] = {pv.x, pv.y, pv.z, pv.w};
    float4 xv = *(const float4*)(x1 + base);
    float xr[4] = {xv.x, xv.y, xv.z, xv.w};
    ushort4 pk;
    unsigned short* pks = (unsigned short*)&pk;
    float mem = 0.f;
    #pragma unroll
    for (int t = 0; t < 4; ++t) {
        float bnv = (xi[t] - mean) * scale + beta;
        mem = mem + (bnv - mem) * 0.5f;
        float s = (mem > 1.0f) ? 1.0f : 0.0f;
        mem *= (1.0f - s);
        xr[t] += s;
        pks[t] = (s > 0.5f) ? 0x3F80 : 0;
    }
    float4 r; r.x = xr[0]; r.y = xr[1]; r.z = xr[2]; r.w = xr[3];
    *(float4*)(x1 + base) = r;
    *(ushort4*)((unsigned short*)s_proj + base) = pk;
}

// ---- fc1 BN+LIF(thr=1) in place on chunk buffer [1536][12544] --------------
__global__ __launch_bounds__(256) void k_bnlif_h(float* __restrict__ hbuf,
                                                 const float* __restrict__ bnp)
{
    int idx = blockIdx.x * 256 + threadIdx.x;
    int o = idx / UC;
    float gamma = bnp[o], beta = bnp[HIDv+o], mean = bnp[2*HIDv+o], var = bnp[3*HIDv+o];
    float scale = gamma / sqrtf(var + 1e-5f);
    size_t base = (size_t)idx * 4;
    float4 hv = *(const float4*)(hbuf + base);
    float xi[4] = {hv.x, hv.y, hv.z, hv.w};
    float s4[4];
    float mem = 0.f;
    #pragma unroll
    for (int t = 0; t < 4; ++t) {
        float bnv = (xi[t] - mean) * scale + beta;
        mem = mem + (bnv - mem) * 0.5f;
        s4[t] = (mem > 1.0f) ? 1.0f : 0.0f;
        mem *= (1.0f - s4[t]);
    }
    float4 r; r.x = s4[0]; r.y = s4[1]; r.z = s4[2]; r.w = s4[3];
    *(float4*)(hbuf + base) = r;
}

// ---- fc2 BN+LIF + out = x(direct) + s_proj + s_fc2, FP32 -------------------
__global__ __launch_bounds__(256) void k_final(const float* __restrict__ h2,
                                               const float* __restrict__ bnp,
                                               const float* __restrict__ x,
                                               const __hip_bfloat16* __restrict__ s_proj,
                                               float* __restrict__ out,
                                               int b0)
{
    int idx = blockIdx.x * 256 + threadIdx.x;
    int c = idx / UC;
    int u = idx - c * UC;
    int bp = u / Nv, n = u - bp * Nv;
    int b = b0 + bp;
    float gamma = bnp[c], beta = bnp[Cv+c], mean = bnp[2*Cv+c], var = bnp[3*Cv+c];
    float scale = gamma / sqrtf(var + 1e-5f);
    float4 hv = *(const float4*)(h2 + (size_t)c * CHUNK + (size_t)u * 4);
    float xi[4] = {hv.x, hv.y, hv.z, hv.w};
    ushort4 sp4 = *(const ushort4*)((const unsigned short*)s_proj +
                                    (size_t)c * Mv + ((size_t)b * Nv + n) * 4);
    unsigned short* sps = (unsigned short*)&sp4;
    float mem = 0.f;
    #pragma unroll
    for (int t = 0; t < 4; ++t) {
        float bnv = (xi[t] - mean) * scale + beta;
        mem = mem + (bnv - mem) * 0.5f;
        float s = (mem > 1.0f) ? 1.0f : 0.0f;
        mem *= (1.0f - s);
        size_t oidx = ((size_t)(t * Bv + b) * Cv + c) * Nv + n;
        float sproj = sps[t] ? 1.0f : 0.0f;
        out[oidx] = x[oidx] + sproj + s;
    }
}

extern "C" void kernel_launch(void* const* d_in, const int* in_sizes, int n_in,
                              void* d_out, int out_size, void* d_ws, size_t ws_size,
                              hipStream_t stream)
{
    const float* x       = (const float*)d_in[0];
    const float* qkvp_w  = (const float*)d_in[1];
    const float* qkvp_bn = (const float*)d_in[2];
    const float* fc1_w   = (const float*)d_in[3];
    const float* fc1_b   = (const float*)d_in[4];
    const float* fc1_bn  = (const float*)d_in[5];
    const float* fc2_w   = (const float*)d_in[6];
    const float* fc2_b   = (const float*)d_in[7];
    const float* fc2_bn  = (const float*)d_in[8];

    float* out1 = (float*)d_out;                    // x_out fp32
    float* out2 = out1 + (size_t)TBv * Cv * Nv;     // v fp32

    float* wsf = (float*)d_ws;
    const size_t S = (size_t)Cv * Mv;
    if (ws_size < 4 * S * sizeof(float)) return;

    float* xp   = wsf;                                  // xp -> x1
    float* ybuf = wsf + S;                              // pre-BN y / attn o
    __hip_bfloat16* qs = (__hip_bfloat16*)(wsf + 2*S);
    __hip_bfloat16* ks = qs + S;
    __hip_bfloat16* vs = qs + 2*S;
    float* pbuf  = wsf + 2*S;                           // proj pre-BN (q/k dead)
    float* hbuf  = wsf + S;                             // fc1 out
    float* h2buf = wsf + 3*S;                           // fc2 out (vs dead)
    __hip_bfloat16* s_proj = (__hip_bfloat16*)(wsf + 3*S + S/2);

    k_transpose_in<<<37632, 256, 0, stream>>>(x, xp);

    // q, k: in-order FMA GEMM (retiled, bitwise == r4) + proven BN/LIF
    for (int br = 0; br < 2; ++br) {
        k_gemm2<<<dim3(392, 3), 256, 0, stream>>>(qkvp_w + (size_t)br*Cv*Cv, xp, ybuf,
                                                  Cv, Mv, Mv, nullptr, 0);
        __hip_bfloat16* sp = (br == 0) ? qs : ks;
        k_bnlif_spike<<<9408, 256, 0, stream>>>(ybuf, qkvp_bn + (size_t)br*4*Cv, sp);
    }
    // v: SSE2-SOP flavor (retiled, bitwise == r11; exact r12 kernel)
    k_vsse2<<<dim3(392, 6), 256, 0, stream>>>(qkvp_w + (size_t)2*Cv*Cv, xp,
                                              qkvp_bn + (size_t)2*4*Cv, vs);

    k_attn<<<dim3(12, 128), 256, 0, stream>>>(qs, ks, vs, ybuf, out2);
    k_attnlif<<<9408, 256, 0, stream>>>(ybuf);

    k_gemm2<<<dim3(392, 3), 256, 0, stream>>>(qkvp_w + (size_t)3*Cv*Cv, ybuf, pbuf,
                                              Cv, Mv, Mv, nullptr, 0);
    k_resid<<<9408, 256, 0, stream>>>(pbuf, qkvp_bn + (size_t)3*4*Cv, xp, s_proj);

    for (int ch = 0; ch < 2; ++ch) {
        k_gemm2<<<dim3(196, 12), 256, 0, stream>>>(fc1_w, xp, hbuf,
                                                   Cv, Mv, CHUNK, fc1_b, ch * CHUNK);
        k_bnlif_h<<<18816, 256, 0, stream>>>(hbuf, fc1_bn);
        k_gemm2<<<dim3(196, 3), 256, 0, stream>>>(fc2_w, hbuf, h2buf,
                                                  HIDv, CHUNK, CHUNK, fc2_b, 0);
        k_final<<<4704, 256, 0, stream>>>(h2buf, fc2_bn, x, s_proj, out1, ch * 16);
    }
}

// Round 15
// 1450.196 us; speedup vs baseline: 1.4952x; 1.0116x over previous
//
#include <hip/hip_runtime.h>
#include <hip/hip_bf16.h>

// Spiking transformer block (Spikformer SSA) on MI355X.
// Layout: [channel][m], m = (b*196+n)*4 + t (time innermost).
//
// CORRECTNESS CONTRACT (r11-r14 PASSED, absmax 0.0 bitwise):
//  - v branch: numpy SSE2-SOP einsum flavor — 4 stripe accumulators (lane=c&3),
//    c ascending, separate __fmul_rn/__fadd_rn, reduce (s0+s2)+(s1+s3),
//    unfused __f*_rn BN/LIF.  - out0 branches: in-order ascending-k fp32 FMA
//    chain per element, zero-init, +bias at end.  - elementwise byte-identical.
// Retiling is bitwise-safe; MFMA / k-splitting / flavor changes are NOT.
// r13 lesson: no __launch_bounds__ min-waves hints on accumulator kernels
// (capped unified VGPR/AGPR file -> scratch spill). r14 lesson: block count /
// TLP is the lever (fc1 2352 blocks beat fc2 588 at equal FLOPs) -> 64x64 tiles.

#define Cv 384
#define Nv 196
#define Mv 25088        // 128*196 columns
#define HIDv 1536
#define Bv 32
#define Zv 6272         // z = b*196+n
#define TBv 128
#define CHUNK 12544     // Mv/2
#define UC 3136         // per-chunk u

// ---- transpose: xp[c*Mv + (b*196+n)*4 + t] = x[((t*32+b)*384+c)*196+n] ----
__global__ __launch_bounds__(256) void k_transpose_in(const float* __restrict__ x,
                                                      float* __restrict__ xp)
{
    int idx = blockIdx.x * 256 + threadIdx.x;
    int c   = idx / Mv;
    int rem = idx - c * Mv;
    int z = rem >> 2, t = rem & 3;
    int b = z / Nv, n = z - b * Nv;
    xp[idx] = x[((size_t)(t * Bv + b) * Cv + c) * Nv + n];
}

// ---- fp32 GEMM, 64x64 tile, BK=16, 4x4 microtile, in-order FMA chains ------
// Bitwise == r4 flavor per element: acc = fmaf(W[o][k], X[k][m], acc), k asc.
__global__ __launch_bounds__(256) void k_gemm3(const float* __restrict__ W,
                                               const float* __restrict__ X,
                                               float* __restrict__ Y,
                                               int K, int ldx, int ldy,
                                               const float* __restrict__ bias,
                                               int cb)
{
    __shared__ float sW[16][68];   // pad 68: 272B rows = 16B-aligned, 2-way free
    __shared__ float sX[16][64];
    int ym0 = blockIdx.x * 64;
    int m0  = cb + ym0;
    int o0  = blockIdx.y * 64;
    int tid = threadIdx.x;
    int wo = tid & 63, wh = tid >> 6;         // W stage: o row, k-quarter
    int xr = tid >> 4, xc = (tid & 15) * 4;   // X stage: k row, float4 col
    int to = tid >> 4, tm = tid & 15;         // microtile coords

    const float* Wp = W + (size_t)(o0 + wo) * K + wh * 4;
    const float* Xp = X + (size_t)xr * ldx + m0 + xc;

    float acc[4][4];
    #pragma unroll
    for (int i = 0; i < 4; ++i)
        #pragma unroll
        for (int j = 0; j < 4; ++j) acc[i][j] = 0.0f;

    for (int k0 = 0; k0 < K; k0 += 16) {
        float4 w4 = *(const float4*)(Wp + k0);
        float4 x4 = *(const float4*)(Xp + (size_t)k0 * ldx);
        __syncthreads();
        sW[wh*4+0][wo] = w4.x;
        sW[wh*4+1][wo] = w4.y;
        sW[wh*4+2][wo] = w4.z;
        sW[wh*4+3][wo] = w4.w;
        *(float4*)&sX[xr][xc] = x4;
        __syncthreads();
        #pragma unroll
        for (int kk = 0; kk < 16; ++kk) {
            float4 a = *(const float4*)&sW[kk][to*4];
            float4 b = *(const float4*)&sX[kk][tm*4];
            float av[4] = {a.x, a.y, a.z, a.w};
            float bv[4] = {b.x, b.y, b.z, b.w};
            #pragma unroll
            for (int i = 0; i < 4; ++i)
                #pragma unroll
                for (int j = 0; j < 4; ++j)
                    acc[i][j] = fmaf(av[i], bv[j], acc[i][j]);
        }
    }
    #pragma unroll
    for (int i = 0; i < 4; ++i) {
        int o = o0 + to*4 + i;
        float bb = bias ? bias[o] : 0.0f;
        float4 r;
        r.x = acc[i][0] + bb; r.y = acc[i][1] + bb;
        r.z = acc[i][2] + bb; r.w = acc[i][3] + bb;
        *(float4*)&Y[(size_t)o * ldy + ym0 + tm*4] = r;
    }
}

// ---- V branch: SSE2-SOP GEMM, 64x64 tile, 4o x 1site microtile -------------
// Bitwise == r11 per element. EXACT r12/r14 version (accs in AGPRs, no hint).
__global__ __launch_bounds__(256) void k_vsse2(const float* __restrict__ W,
                                               const float* __restrict__ X,
                                               const float* __restrict__ bnp,
                                               __hip_bfloat16* __restrict__ Y)
{
    __shared__ float sW[32][68];    // [kk][o], pad 68 keeps 16B align + 2-way
    __shared__ float sX[32][64];
    int m0 = blockIdx.x * 64;
    int o0 = blockIdx.y * 64;
    int tid = threadIdx.x;
    int to = tid >> 4, tm = tid & 15;

    float acc[4][4][4];     // [stripe][o'][e]
    #pragma unroll
    for (int s = 0; s < 4; ++s)
        #pragma unroll
        for (int op = 0; op < 4; ++op)
            #pragma unroll
            for (int e = 0; e < 4; ++e) acc[s][op][e] = 0.0f;

    int wq_o = tid >> 3, wq_c = tid & 7;      // W stage: 64 o x 8 float4-cols
    int xs_r = tid >> 3, xs_c = (tid & 7) * 8; // X stage: 32 rows x 2 float4

    for (int blk = 0; blk < 12; ++blk) {
        int k0 = blk * 32;
        __syncthreads();
        {   // stage W: sW[kk][o] = W[o0+o][k0+kk]
            float4 w4 = *(const float4*)(W + (size_t)(o0 + wq_o) * Cv + k0 + wq_c*4);
            sW[wq_c*4+0][wq_o] = w4.x;
            sW[wq_c*4+1][wq_o] = w4.y;
            sW[wq_c*4+2][wq_o] = w4.z;
            sW[wq_c*4+3][wq_o] = w4.w;
            float4 w5 = *(const float4*)(W + (size_t)(o0 + 32 + wq_o) * Cv + k0 + wq_c*4);
            sW[wq_c*4+0][32 + wq_o] = w5.x;
            sW[wq_c*4+1][32 + wq_o] = w5.y;
            sW[wq_c*4+2][32 + wq_o] = w5.z;
            sW[wq_c*4+3][32 + wq_o] = w5.w;
        }
        {   // stage X: sX[kk][m'] = X[k0+kk][m0+m']
            const float* Xp = X + (size_t)(k0 + xs_r) * Mv + m0 + xs_c;
            *(float4*)&sX[xs_r][xs_c]     = *(const float4*)(Xp);
            *(float4*)&sX[xs_r][xs_c + 4] = *(const float4*)(Xp + 4);
        }
        __syncthreads();
        #pragma unroll
        for (int j = 0; j < 8; ++j) {
            #pragma unroll
            for (int s = 0; s < 4; ++s) {
                int kk = j * 4 + s;             // c = k0 + j*4 + s  (stripe c&3)
                float4 w4 = *(const float4*)&sW[kk][to*4];
                float4 x4 = *(const float4*)&sX[kk][tm*4];
                float wv[4] = {w4.x, w4.y, w4.z, w4.w};
                float xv[4] = {x4.x, x4.y, x4.z, x4.w};
                #pragma unroll
                for (int op = 0; op < 4; ++op)
                    #pragma unroll
                    for (int e = 0; e < 4; ++e)
                        acc[s][op][e] = __fadd_rn(acc[s][op][e],
                                                  __fmul_rn(wv[op], xv[e]));
            }
        }
    }

    #pragma unroll
    for (int op = 0; op < 4; ++op) {
        int o = o0 + to*4 + op;
        float inv = __fdiv_rn(1.0f, __fsqrt_rn(__fadd_rn(bnp[3*Cv + o], 1e-5f)));
        float sc  = __fmul_rn(bnp[o], inv);
        float mu  = bnp[2*Cv + o];
        float be  = bnp[Cv + o];
        float mem = 0.0f;
        ushort4 pk;
        unsigned short* pks = (unsigned short*)&pk;
        #pragma unroll
        for (int e = 0; e < 4; ++e) {
            float tot = __fadd_rn(__fadd_rn(acc[0][op][e], acc[2][op][e]),
                                  __fadd_rn(acc[1][op][e], acc[3][op][e]));
            float bn = __fadd_rn(__fmul_rn(__fsub_rn(tot, mu), sc), be);
            mem = __fadd_rn(mem, __fmul_rn(__fsub_rn(bn, mem), 0.5f));
            int s = (mem > 1.0f);
            mem = s ? 0.0f : mem;
            pks[e] = s ? 0x3F80 : 0;
        }
        *(ushort4*)((unsigned short*)Y + (size_t)o * Mv + m0 + tm * 4) = pk;
    }
}

// ---- BN + LIF(thr=1) -> bf16 spikes (r4 flavor; q/k branches) --------------
__global__ __launch_bounds__(256) void k_bnlif_spike(const float* __restrict__ y,
                                                     const float* __restrict__ bnp,
                                                     __hip_bfloat16* __restrict__ sp)
{
    int idx = blockIdx.x * 256 + threadIdx.x;
    int c = idx / Zv;
    float gamma = bnp[c], beta = bnp[Cv+c], mean = bnp[2*Cv+c], var = bnp[3*Cv+c];
    float scale = gamma / sqrtf(var + 1e-5f);
    size_t base = (size_t)idx * 4;
    float4 yv = *(const float4*)(y + base);
    float xi[4] = {yv.x, yv.y, yv.z, yv.w};
    ushort4 pk;
    unsigned short* pks = (unsigned short*)&pk;
    float mem = 0.f;
    #pragma unroll
    for (int t = 0; t < 4; ++t) {
        float xv = (xi[t] - mean) * scale + beta;
        mem = mem + (xv - mem) * 0.5f;
        float s = (mem > 1.0f) ? 1.0f : 0.0f;
        mem *= (1.0f - s);
        pks[t] = (s > 0.5f) ? 0x3F80 : 0;
    }
    *(ushort4*)((unsigned short*)sp + base) = pk;
}

// ---- attention per (h, tbl): popcount QK^T, exact fp32 PV ------------------
__global__ __launch_bounds__(256) void k_attn(const __hip_bfloat16* __restrict__ qs,
                                              const __hip_bfloat16* __restrict__ ks,
                                              const __hip_bfloat16* __restrict__ vs,
                                              float* __restrict__ o_chan,
                                              float* __restrict__ v_out)
{
    int h = blockIdx.x, tbl = blockIdx.y;
    int t = tbl >> 5, b = tbl & 31;
    int tid = threadIdx.x;
    __shared__ unsigned kmask[196];
    __shared__ float vf[196][36];
    size_t chb  = (size_t)h * 32 * Mv;
    size_t colb = (size_t)b * Nv * 4 + t;

    for (int e = tid; e < Nv * 32; e += 256) {
        int dd = e / Nv, n = e - dd * Nv;
        vf[n][dd] = __bfloat162float(vs[chb + (size_t)dd * Mv + colb + (size_t)n * 4]);
    }
    unsigned qm = 0;
    if (tid < Nv) {
        unsigned km = 0;
        #pragma unroll
        for (int dd = 0; dd < 32; ++dd) {
            size_t off = chb + (size_t)dd * Mv + colb + (size_t)tid * 4;
            km |= (__bfloat162float(ks[off]) > 0.5f ? 1u : 0u) << dd;
            qm |= (__bfloat162float(qs[off]) > 0.5f ? 1u : 0u) << dd;
        }
        kmask[tid] = km;
    }
    __syncthreads();
    for (int e = tid; e < Nv * 32; e += 256) {
        int n = e >> 5, dd = e & 31;
        v_out[((size_t)(tbl * 12 + h) * Nv + n) * 32 + dd] = vf[n][dd];
    }
    if (tid < Nv) {
        float acc[32] = {};
        for (int nk = 0; nk < Nv; ++nk) {
            float a = (float)__popc(qm & kmask[nk]) * 0.125f;   // exact
            #pragma unroll
            for (int dd = 0; dd < 32; ++dd) acc[dd] += a * vf[nk][dd];
        }
        #pragma unroll
        for (int dd = 0; dd < 32; ++dd)
            o_chan[chb + (size_t)dd * Mv + colb + (size_t)tid * 4] = acc[dd];
    }
}

// ---- attn LIF (thr=0.5): exact (dyadic grid) -------------------------------
__global__ __launch_bounds__(256) void k_attnlif(float* __restrict__ o)
{
    int idx = blockIdx.x * 256 + threadIdx.x;
    size_t base = (size_t)idx * 4;
    float4 v = *(const float4*)(o + base);
    float xi[4] = {v.x, v.y, v.z, v.w};
    float s4[4];
    float mem = 0.f;
    #pragma unroll
    for (int t = 0; t < 4; ++t) {
        mem = mem + (xi[t] - mem) * 0.5f;
        s4[t] = (mem > 0.5f) ? 1.0f : 0.0f;
        mem *= (1.0f - s4[t]);
    }
    float4 r; r.x = s4[0]; r.y = s4[1]; r.z = s4[2]; r.w = s4[3];
    *(float4*)(o + base) = r;
}

// ---- proj BN+LIF(thr=1): x1 += s and s_proj (bf16) -------------------------
__global__ __launch_bounds__(256) void k_resid(const float* __restrict__ p,
                                               const float* __restrict__ bnp,
                                               float* __restrict__ x1,
                                               __hip_bfloat16* __restrict__ s_proj)
{
    int idx = blockIdx.x * 256 + threadIdx.x;
    int c = idx / Zv;
    float gamma = bnp[c], beta = bnp[Cv+c], mean = bnp[2*Cv+c], var = bnp[3*Cv+c];
    float scale = gamma / sqrtf(var + 1e-5f);
    size_t base = (size_t)idx * 4;
    float4 pv = *(const float4*)(p + base);
    float xi[4] = {pv.x, pv.y, pv.z, pv.w};
    float4 xv = *(const float4*)(x1 + base);
    float xr[4] = {xv.x, xv.y, xv.z, xv.w};
    ushort4 pk;
    unsigned short* pks = (unsigned short*)&pk;
    float mem = 0.f;
    #pragma unroll
    for (int t = 0; t < 4; ++t) {
        float bnv = (xi[t] - mean) * scale + beta;
        mem = mem + (bnv - mem) * 0.5f;
        float s = (mem > 1.0f) ? 1.0f : 0.0f;
        mem *= (1.0f - s);
        xr[t] += s;
        pks[t] = (s > 0.5f) ? 0x3F80 : 0;
    }
    float4 r; r.x = xr[0]; r.y = xr[1]; r.z = xr[2]; r.w = xr[3];
    *(float4*)(x1 + base) = r;
    *(ushort4*)((unsigned short*)s_proj + base) = pk;
}

// ---- fc1 BN+LIF(thr=1) in place on chunk buffer [1536][12544] --------------
__global__ __launch_bounds__(256) void k_bnlif_h(float* __restrict__ hbuf,
                                                 const float* __restrict__ bnp)
{
    int idx = blockIdx.x * 256 + threadIdx.x;
    int o = idx / UC;
    float gamma = bnp[o], beta = bnp[HIDv+o], mean = bnp[2*HIDv+o], var = bnp[3*HIDv+o];
    float scale = gamma / sqrtf(var + 1e-5f);
    size_t base = (size_t)idx * 4;
    float4 hv = *(const float4*)(hbuf + base);
    float xi[4] = {hv.x, hv.y, hv.z, hv.w};
    float s4[4];
    float mem = 0.f;
    #pragma unroll
    for (int t = 0; t < 4; ++t) {
        float bnv = (xi[t] - mean) * scale + beta;
        mem = mem + (bnv - mem) * 0.5f;
        s4[t] = (mem > 1.0f) ? 1.0f : 0.0f;
        mem *= (1.0f - s4[t]);
    }
    float4 r; r.x = s4[0]; r.y = s4[1]; r.z = s4[2]; r.w = s4[3];
    *(float4*)(hbuf + base) = r;
}

// ---- fc2 BN+LIF + out = x(direct) + s_proj + s_fc2, FP32 -------------------
__global__ __launch_bounds__(256) void k_final(const float* __restrict__ h2,
                                               const float* __restrict__ bnp,
                                               const float* __restrict__ x,
                                               const __hip_bfloat16* __restrict__ s_proj,
                                               float* __restrict__ out,
                                               int b0)
{
    int idx = blockIdx.x * 256 + threadIdx.x;
    int c = idx / UC;
    int u = idx - c * UC;
    int bp = u / Nv, n = u - bp * Nv;
    int b = b0 + bp;
    float gamma = bnp[c], beta = bnp[Cv+c], mean = bnp[2*Cv+c], var = bnp[3*Cv+c];
    float scale = gamma / sqrtf(var + 1e-5f);
    float4 hv = *(const float4*)(h2 + (size_t)c * CHUNK + (size_t)u * 4);
    float xi[4] = {hv.x, hv.y, hv.z, hv.w};
    ushort4 sp4 = *(const ushort4*)((const unsigned short*)s_proj +
                                    (size_t)c * Mv + ((size_t)b * Nv + n) * 4);
    unsigned short* sps = (unsigned short*)&sp4;
    float mem = 0.f;
    #pragma unroll
    for (int t = 0; t < 4; ++t) {
        float bnv = (xi[t] - mean) * scale + beta;
        mem = mem + (bnv - mem) * 0.5f;
        float s = (mem > 1.0f) ? 1.0f : 0.0f;
        mem *= (1.0f - s);
        size_t oidx = ((size_t)(t * Bv + b) * Cv + c) * Nv + n;
        float sproj = sps[t] ? 1.0f : 0.0f;
        out[oidx] = x[oidx] + sproj + s;
    }
}

extern "C" void kernel_launch(void* const* d_in, const int* in_sizes, int n_in,
                              void* d_out, int out_size, void* d_ws, size_t ws_size,
                              hipStream_t stream)
{
    const float* x       = (const float*)d_in[0];
    const float* qkvp_w  = (const float*)d_in[1];
    const float* qkvp_bn = (const float*)d_in[2];
    const float* fc1_w   = (const float*)d_in[3];
    const float* fc1_b   = (const float*)d_in[4];
    const float* fc1_bn  = (const float*)d_in[5];
    const float* fc2_w   = (const float*)d_in[6];
    const float* fc2_b   = (const float*)d_in[7];
    const float* fc2_bn  = (const float*)d_in[8];

    float* out1 = (float*)d_out;                    // x_out fp32
    float* out2 = out1 + (size_t)TBv * Cv * Nv;     // v fp32

    float* wsf = (float*)d_ws;
    const size_t S = (size_t)Cv * Mv;
    if (ws_size < 4 * S * sizeof(float)) return;

    float* xp   = wsf;                                  // xp -> x1
    float* ybuf = wsf + S;                              // pre-BN y / attn o
    __hip_bfloat16* qs = (__hip_bfloat16*)(wsf + 2*S);
    __hip_bfloat16* ks = qs + S;
    __hip_bfloat16* vs = qs + 2*S;
    float* pbuf  = wsf + 2*S;                           // proj pre-BN (q/k dead)
    float* hbuf  = wsf + S;                             // fc1 out
    float* h2buf = wsf + 3*S;                           // fc2 out (vs dead)
    __hip_bfloat16* s_proj = (__hip_bfloat16*)(wsf + 3*S + S/2);

    k_transpose_in<<<37632, 256, 0, stream>>>(x, xp);

    // q, k: in-order FMA GEMM (64x64 retile, bitwise == r4) + proven BN/LIF
    for (int br = 0; br < 2; ++br) {
        k_gemm3<<<dim3(392, 6), 256, 0, stream>>>(qkvp_w + (size_t)br*Cv*Cv, xp, ybuf,
                                                  Cv, Mv, Mv, nullptr, 0);
        __hip_bfloat16* sp = (br == 0) ? qs : ks;
        k_bnlif_spike<<<9408, 256, 0, stream>>>(ybuf, qkvp_bn + (size_t)br*4*Cv, sp);
    }
    // v: SSE2-SOP flavor (exact r12/r14 kernel)
    k_vsse2<<<dim3(392, 6), 256, 0, stream>>>(qkvp_w + (size_t)2*Cv*Cv, xp,
                                              qkvp_bn + (size_t)2*4*Cv, vs);

    k_attn<<<dim3(12, 128), 256, 0, stream>>>(qs, ks, vs, ybuf, out2);
    k_attnlif<<<9408, 256, 0, stream>>>(ybuf);

    k_gemm3<<<dim3(392, 6), 256, 0, stream>>>(qkvp_w + (size_t)3*Cv*Cv, ybuf, pbuf,
                                              Cv, Mv, Mv, nullptr, 0);
    k_resid<<<9408, 256, 0, stream>>>(pbuf, qkvp_bn + (size_t)3*4*Cv, xp, s_proj);

    for (int ch = 0; ch < 2; ++ch) {
        k_gemm3<<<dim3(196, 24), 256, 0, stream>>>(fc1_w, xp, hbuf,
                                                   Cv, Mv, CHUNK, fc1_b, ch * CHUNK);
        k_bnlif_h<<<18816, 256, 0, stream>>>(hbuf, fc1_bn);
        k_gemm3<<<dim3(196, 6), 256, 0, stream>>>(fc2_w, hbuf, h2buf,
                                                  HIDv, CHUNK, CHUNK, fc2_b, 0);
        k_final<<<4704, 256, 0, stream>>>(h2buf, fc2_bn, x, s_proj, out1, ch * 16);
    }
}

// Round 16
// 1366.381 us; speedup vs baseline: 1.5870x; 1.0613x over previous
//
#include <hip/hip_runtime.h>
#include <hip/hip_bf16.h>

// Spiking transformer block (Spikformer SSA) on MI355X.
// Layout: [channel][m], m = (b*196+n)*4 + t (time innermost).
//
// CORRECTNESS CONTRACT (r11-r15 PASSED, absmax 0.0 bitwise):
//  - v branch: numpy SSE2-SOP einsum flavor (k_vsse2, byte-identical r12).
//  - out0 GEMMs: in-order ascending-k fp32 FMA chain per element, zero-init,
//    plain +bias at end (r4 flavor).  - BN/LIF: either contracted plain ops
//    (r4 corner) or explicit __f*_rn (r7 corner) — BOTH proven on out0.
//    fc1 fused epilogue uses r7's EXACT explicit form (ref = separate np
//    ufuncs == explicit form; r7 passed fc1 with it).
//  - bf16 spike storage is exact ({0,1}); retiling is bitwise-safe.
// r13: no min-waves hints on accumulator kernels (AGPR budget). r15: 4x4
// microtile is LDS-balance-capped at ~55% VALU -> 4x8 split microtile.

#define Cv 384
#define Nv 196
#define Mv 25088        // 128*196 columns
#define HIDv 1536
#define Bv 32
#define Zv 6272         // z = b*196+n
#define TBv 128

// ---- transpose: xp[c*Mv + (b*196+n)*4 + t] = x[((t*32+b)*384+c)*196+n] ----
__global__ __launch_bounds__(256) void k_transpose_in(const float* __restrict__ x,
                                                      float* __restrict__ xp)
{
    int idx = blockIdx.x * 256 + threadIdx.x;
    int c   = idx / Mv;
    int rem = idx - c * Mv;
    int z = rem >> 2, t = rem & 3;
    int b = z / Nv, n = z - b * Nv;
    xp[idx] = x[((size_t)(t * Bv + b) * Cv + c) * Nv + n];
}

// ---- fp32 GEMM, 64o x 128m tile, BK=16, 4x8 split microtile ----------------
// Bitwise == r4 flavor per element: acc = fmaf(W[o][k], X[k][m], acc), k asc,
// zero-init, plain +bias at end. XBF16: X is bf16 spikes (exact {0,1}).
template<int XBF16>
__global__ __launch_bounds__(256) void k_gemm4(const float* __restrict__ W,
                                               const void* __restrict__ Xv,
                                               float* __restrict__ Y,
                                               int K, int ldx, int ldy,
                                               const float* __restrict__ bias,
                                               int cb)
{
    __shared__ float sW[16][68];
    __shared__ float sX[16][128];
    int ym0 = blockIdx.x * 128;
    int m0  = cb + ym0;
    int o0  = blockIdx.y * 64;
    int tid = threadIdx.x;
    int wo = tid & 63, wh = tid >> 6;         // W stage: o row, k-quarter
    int xr = tid >> 4, xc = (tid & 15) * 8;   // X stage: k row, 8-col group
    int to = tid >> 4, tm = tid & 15;         // microtile coords

    const float* Wp = W + (size_t)(o0 + wo) * K + wh * 4;

    float acc[4][8];
    #pragma unroll
    for (int i = 0; i < 4; ++i)
        #pragma unroll
        for (int j = 0; j < 8; ++j) acc[i][j] = 0.0f;

    for (int k0 = 0; k0 < K; k0 += 16) {
        float4 w4 = *(const float4*)(Wp + k0);
        float xf[8];
        if (XBF16) {
            const unsigned short* Xb = (const unsigned short*)Xv;
            uint4 u = *(const uint4*)(Xb + (size_t)(k0 + xr) * ldx + m0 + xc);
            unsigned uu[4] = {u.x, u.y, u.z, u.w};
            #pragma unroll
            for (int q = 0; q < 4; ++q) {
                xf[2*q]   = __uint_as_float((uu[q] & 0xFFFFu) << 16);
                xf[2*q+1] = __uint_as_float(uu[q] & 0xFFFF0000u);
            }
        } else {
            const float* Xf = (const float*)Xv;
            float4 xa = *(const float4*)(Xf + (size_t)(k0 + xr) * ldx + m0 + xc);
            float4 xb = *(const float4*)(Xf + (size_t)(k0 + xr) * ldx + m0 + xc + 4);
            xf[0]=xa.x; xf[1]=xa.y; xf[2]=xa.z; xf[3]=xa.w;
            xf[4]=xb.x; xf[5]=xb.y; xf[6]=xb.z; xf[7]=xb.w;
        }
        __syncthreads();
        sW[wh*4+0][wo] = w4.x;
        sW[wh*4+1][wo] = w4.y;
        sW[wh*4+2][wo] = w4.z;
        sW[wh*4+3][wo] = w4.w;
        *(float4*)&sX[xr][xc]     = *(float4*)&xf[0];
        *(float4*)&sX[xr][xc + 4] = *(float4*)&xf[4];
        __syncthreads();
        #pragma unroll
        for (int kk = 0; kk < 16; ++kk) {
            float4 a  = *(const float4*)&sW[kk][to*4];
            float4 b0 = *(const float4*)&sX[kk][tm*4];
            float4 b1 = *(const float4*)&sX[kk][64 + tm*4];
            float av[4] = {a.x, a.y, a.z, a.w};
            float bv[8] = {b0.x,b0.y,b0.z,b0.w,b1.x,b1.y,b1.z,b1.w};
            #pragma unroll
            for (int i = 0; i < 4; ++i)
                #pragma unroll
                for (int j = 0; j < 8; ++j)
                    acc[i][j] = fmaf(av[i], bv[j], acc[i][j]);
        }
    }
    #pragma unroll
    for (int i = 0; i < 4; ++i) {
        int o = o0 + to*4 + i;
        float bb = bias ? bias[o] : 0.0f;
        float4 r0, r1;
        r0.x = acc[i][0] + bb; r0.y = acc[i][1] + bb;
        r0.z = acc[i][2] + bb; r0.w = acc[i][3] + bb;
        r1.x = acc[i][4] + bb; r1.y = acc[i][5] + bb;
        r1.z = acc[i][6] + bb; r1.w = acc[i][7] + bb;
        *(float4*)&Y[(size_t)o * ldy + ym0 + tm*4]      = r0;
        *(float4*)&Y[(size_t)o * ldy + ym0 + 64 + tm*4] = r1;
    }
}

// ---- fc1: GEMM(4x8) + fused bias+BN+LIF (r7 explicit epilogue) -> bf16 -----
// GEMM chain bitwise == r4 flavor; epilogue == r7's exact __f*_rn sequence.
__global__ __launch_bounds__(256) void k_fc1(const float* __restrict__ W,
                                             const float* __restrict__ X,
                                             const float* __restrict__ bias,
                                             const float* __restrict__ bnp,
                                             __hip_bfloat16* __restrict__ H)
{
    __shared__ float sW[16][68];
    __shared__ float sX[16][128];
    int ym0 = blockIdx.x * 128;
    int o0  = blockIdx.y * 64;
    int tid = threadIdx.x;
    int wo = tid & 63, wh = tid >> 6;
    int xr = tid >> 4, xc = (tid & 15) * 8;
    int to = tid >> 4, tm = tid & 15;

    const float* Wp = W + (size_t)(o0 + wo) * Cv + wh * 4;

    float acc[4][8];
    #pragma unroll
    for (int i = 0; i < 4; ++i)
        #pragma unroll
        for (int j = 0; j < 8; ++j) acc[i][j] = 0.0f;

    for (int k0 = 0; k0 < Cv; k0 += 16) {
        float4 w4 = *(const float4*)(Wp + k0);
        float4 xa = *(const float4*)(X + (size_t)(k0 + xr) * Mv + ym0 + xc);
        float4 xb = *(const float4*)(X + (size_t)(k0 + xr) * Mv + ym0 + xc + 4);
        __syncthreads();
        sW[wh*4+0][wo] = w4.x;
        sW[wh*4+1][wo] = w4.y;
        sW[wh*4+2][wo] = w4.z;
        sW[wh*4+3][wo] = w4.w;
        *(float4*)&sX[xr][xc]     = xa;
        *(float4*)&sX[xr][xc + 4] = xb;
        __syncthreads();
        #pragma unroll
        for (int kk = 0; kk < 16; ++kk) {
            float4 a  = *(const float4*)&sW[kk][to*4];
            float4 b0 = *(const float4*)&sX[kk][tm*4];
            float4 b1 = *(const float4*)&sX[kk][64 + tm*4];
            float av[4] = {a.x, a.y, a.z, a.w};
            float bv[8] = {b0.x,b0.y,b0.z,b0.w,b1.x,b1.y,b1.z,b1.w};
            #pragma unroll
            for (int i = 0; i < 4; ++i)
                #pragma unroll
                for (int j = 0; j < 8; ++j)
                    acc[i][j] = fmaf(av[i], bv[j], acc[i][j]);
        }
    }
    #pragma unroll
    for (int i = 0; i < 4; ++i) {
        int o = o0 + to*4 + i;
        // r7's exact explicit np-ufunc BN flavor:
        float inv = __fdiv_rn(1.0f, __fsqrt_rn(__fadd_rn(bnp[3*HIDv + o], 1e-5f)));
        float sc  = __fmul_rn(bnp[o], inv);
        float mu  = bnp[2*HIDv + o];
        float be  = bnp[HIDv + o];
        #pragma unroll
        for (int half = 0; half < 2; ++half) {
            float mem = 0.0f;
            ushort4 pk;
            unsigned short* pks = (unsigned short*)&pk;
            #pragma unroll
            for (int t = 0; t < 4; ++t) {
                float val = __fadd_rn(acc[i][half*4 + t], bias[o]);
                float bn  = __fadd_rn(__fmul_rn(__fsub_rn(val, mu), sc), be);
                mem = __fadd_rn(mem, __fmul_rn(__fsub_rn(bn, mem), 0.5f));
                int s = (mem > 1.0f);
                mem = s ? 0.0f : mem;
                pks[t] = s ? 0x3F80 : 0;
            }
            *(ushort4*)((unsigned short*)H + (size_t)o * Mv + ym0 + half*64 + tm*4) = pk;
        }
    }
}

// ---- V branch: SSE2-SOP GEMM (byte-identical r12/r14/r15 kernel) -----------
__global__ __launch_bounds__(256) void k_vsse2(const float* __restrict__ W,
                                               const float* __restrict__ X,
                                               const float* __restrict__ bnp,
                                               __hip_bfloat16* __restrict__ Y)
{
    __shared__ float sW[32][68];
    __shared__ float sX[32][64];
    int m0 = blockIdx.x * 64;
    int o0 = blockIdx.y * 64;
    int tid = threadIdx.x;
    int to = tid >> 4, tm = tid & 15;

    float acc[4][4][4];
    #pragma unroll
    for (int s = 0; s < 4; ++s)
        #pragma unroll
        for (int op = 0; op < 4; ++op)
            #pragma unroll
            for (int e = 0; e < 4; ++e) acc[s][op][e] = 0.0f;

    int wq_o = tid >> 3, wq_c = tid & 7;
    int xs_r = tid >> 3, xs_c = (tid & 7) * 8;

    for (int blk = 0; blk < 12; ++blk) {
        int k0 = blk * 32;
        __syncthreads();
        {
            float4 w4 = *(const float4*)(W + (size_t)(o0 + wq_o) * Cv + k0 + wq_c*4);
            sW[wq_c*4+0][wq_o] = w4.x;
            sW[wq_c*4+1][wq_o] = w4.y;
            sW[wq_c*4+2][wq_o] = w4.z;
            sW[wq_c*4+3][wq_o] = w4.w;
            float4 w5 = *(const float4*)(W + (size_t)(o0 + 32 + wq_o) * Cv + k0 + wq_c*4);
            sW[wq_c*4+0][32 + wq_o] = w5.x;
            sW[wq_c*4+1][32 + wq_o] = w5.y;
            sW[wq_c*4+2][32 + wq_o] = w5.z;
            sW[wq_c*4+3][32 + wq_o] = w5.w;
        }
        {
            const float* Xp = X + (size_t)(k0 + xs_r) * Mv + m0 + xs_c;
            *(float4*)&sX[xs_r][xs_c]     = *(const float4*)(Xp);
            *(float4*)&sX[xs_r][xs_c + 4] = *(const float4*)(Xp + 4);
        }
        __syncthreads();
        #pragma unroll
        for (int j = 0; j < 8; ++j) {
            #pragma unroll
            for (int s = 0; s < 4; ++s) {
                int kk = j * 4 + s;
                float4 w4 = *(const float4*)&sW[kk][to*4];
                float4 x4 = *(const float4*)&sX[kk][tm*4];
                float wv[4] = {w4.x, w4.y, w4.z, w4.w};
                float xv[4] = {x4.x, x4.y, x4.z, x4.w};
                #pragma unroll
                for (int op = 0; op < 4; ++op)
                    #pragma unroll
                    for (int e = 0; e < 4; ++e)
                        acc[s][op][e] = __fadd_rn(acc[s][op][e],
                                                  __fmul_rn(wv[op], xv[e]));
            }
        }
    }

    #pragma unroll
    for (int op = 0; op < 4; ++op) {
        int o = o0 + to*4 + op;
        float inv = __fdiv_rn(1.0f, __fsqrt_rn(__fadd_rn(bnp[3*Cv + o], 1e-5f)));
        float sc  = __fmul_rn(bnp[o], inv);
        float mu  = bnp[2*Cv + o];
        float be  = bnp[Cv + o];
        float mem = 0.0f;
        ushort4 pk;
        unsigned short* pks = (unsigned short*)&pk;
        #pragma unroll
        for (int e = 0; e < 4; ++e) {
            float tot = __fadd_rn(__fadd_rn(acc[0][op][e], acc[2][op][e]),
                                  __fadd_rn(acc[1][op][e], acc[3][op][e]));
            float bn = __fadd_rn(__fmul_rn(__fsub_rn(tot, mu), sc), be);
            mem = __fadd_rn(mem, __fmul_rn(__fsub_rn(bn, mem), 0.5f));
            int s = (mem > 1.0f);
            mem = s ? 0.0f : mem;
            pks[e] = s ? 0x3F80 : 0;
        }
        *(ushort4*)((unsigned short*)Y + (size_t)o * Mv + m0 + tm * 4) = pk;
    }
}

// ---- BN + LIF(thr=1) -> bf16 spikes (byte-identical; q/k branches) ---------
__global__ __launch_bounds__(256) void k_bnlif_spike(const float* __restrict__ y,
                                                     const float* __restrict__ bnp,
                                                     __hip_bfloat16* __restrict__ sp)
{
    int idx = blockIdx.x * 256 + threadIdx.x;
    int c = idx / Zv;
    float gamma = bnp[c], beta = bnp[Cv+c], mean = bnp[2*Cv+c], var = bnp[3*Cv+c];
    float scale = gamma / sqrtf(var + 1e-5f);
    size_t base = (size_t)idx * 4;
    float4 yv = *(const float4*)(y + base);
    float xi[4] = {yv.x, yv.y, yv.z, yv.w};
    ushort4 pk;
    unsigned short* pks = (unsigned short*)&pk;
    float mem = 0.f;
    #pragma unroll
    for (int t = 0; t < 4; ++t) {
        float xv = (xi[t] - mean) * scale + beta;
        mem = mem + (xv - mem) * 0.5f;
        float s = (mem > 1.0f) ? 1.0f : 0.0f;
        mem *= (1.0f - s);
        pks[t] = (s > 0.5f) ? 0x3F80 : 0;
    }
    *(ushort4*)((unsigned short*)sp + base) = pk;
}

// ---- attention per (h, tbl): popcount QK^T, exact fp32 PV ------------------
__global__ __launch_bounds__(256) void k_attn(const __hip_bfloat16* __restrict__ qs,
                                              const __hip_bfloat16* __restrict__ ks,
                                              const __hip_bfloat16* __restrict__ vs,
                                              float* __restrict__ o_chan,
                                              float* __restrict__ v_out)
{
    int h = blockIdx.x, tbl = blockIdx.y;
    int t = tbl >> 5, b = tbl & 31;
    int tid = threadIdx.x;
    __shared__ unsigned kmask[196];
    __shared__ float vf[196][36];
    size_t chb  = (size_t)h * 32 * Mv;
    size_t colb = (size_t)b * Nv * 4 + t;

    for (int e = tid; e < Nv * 32; e += 256) {
        int dd = e / Nv, n = e - dd * Nv;
        vf[n][dd] = __bfloat162float(vs[chb + (size_t)dd * Mv + colb + (size_t)n * 4]);
    }
    unsigned qm = 0;
    if (tid < Nv) {
        unsigned km = 0;
        #pragma unroll
        for (int dd = 0; dd < 32; ++dd) {
            size_t off = chb + (size_t)dd * Mv + colb + (size_t)tid * 4;
            km |= (__bfloat162float(ks[off]) > 0.5f ? 1u : 0u) << dd;
            qm |= (__bfloat162float(qs[off]) > 0.5f ? 1u : 0u) << dd;
        }
        kmask[tid] = km;
    }
    __syncthreads();
    for (int e = tid; e < Nv * 32; e += 256) {
        int n = e >> 5, dd = e & 31;
        v_out[((size_t)(tbl * 12 + h) * Nv + n) * 32 + dd] = vf[n][dd];
    }
    if (tid < Nv) {
        float acc[32] = {};
        for (int nk = 0; nk < Nv; ++nk) {
            float a = (float)__popc(qm & kmask[nk]) * 0.125f;
            #pragma unroll
            for (int dd = 0; dd < 32; ++dd) acc[dd] += a * vf[nk][dd];
        }
        #pragma unroll
        for (int dd = 0; dd < 32; ++dd)
            o_chan[chb + (size_t)dd * Mv + colb + (size_t)tid * 4] = acc[dd];
    }
}

// ---- attn LIF (thr=0.5): exact (dyadic grid) -------------------------------
__global__ __launch_bounds__(256) void k_attnlif(float* __restrict__ o)
{
    int idx = blockIdx.x * 256 + threadIdx.x;
    size_t base = (size_t)idx * 4;
    float4 v = *(const float4*)(o + base);
    float xi[4] = {v.x, v.y, v.z, v.w};
    float s4[4];
    float mem = 0.f;
    #pragma unroll
    for (int t = 0; t < 4; ++t) {
        mem = mem + (xi[t] - mem) * 0.5f;
        s4[t] = (mem > 0.5f) ? 1.0f : 0.0f;
        mem *= (1.0f - s4[t]);
    }
    float4 r; r.x = s4[0]; r.y = s4[1]; r.z = s4[2]; r.w = s4[3];
    *(float4*)(o + base) = r;
}

// ---- proj BN+LIF(thr=1): x1 += s and s_proj (byte-identical) ---------------
__global__ __launch_bounds__(256) void k_resid(const float* __restrict__ p,
                                               const float* __restrict__ bnp,
                                               float* __restrict__ x1,
                                               __hip_bfloat16* __restrict__ s_proj)
{
    int idx = blockIdx.x * 256 + threadIdx.x;
    int c = idx / Zv;
    float gamma = bnp[c], beta = bnp[Cv+c], mean = bnp[2*Cv+c], var = bnp[3*Cv+c];
    float scale = gamma / sqrtf(var + 1e-5f);
    size_t base = (size_t)idx * 4;
    float4 pv = *(const float4*)(p + base);
    float xi[4] = {pv.x, pv.y, pv.z, pv.w};
    float4 xv = *(const float4*)(x1 + base);
    float xr[4] = {xv.x, xv.y, xv.z, xv.w};
    ushort4 pk;
    unsigned short* pks = (unsigned short*)&pk;
    float mem = 0.f;
    #pragma unroll
    for (int t = 0; t < 4; ++t) {
        float bnv = (xi[t] - mean) * scale + beta;
        mem = mem + (bnv - mem) * 0.5f;
        float s = (mem > 1.0f) ? 1.0f : 0.0f;
        mem *= (1.0f - s);
        xr[t] += s;
        pks[t] = (s > 0.5f) ? 0x3F80 : 0;
    }
    float4 r; r.x = xr[0]; r.y = xr[1]; r.z = xr[2]; r.w = xr[3];
    *(float4*)(x1 + base) = r;
    *(ushort4*)((unsigned short*)s_proj + base) = pk;
}

// ---- fc2 BN+LIF + out = x + s_proj + s_fc2 (full-M; same arithmetic) -------
__global__ __launch_bounds__(256) void k_final(const float* __restrict__ h2,
                                               const float* __restrict__ bnp,
                                               const float* __restrict__ x,
                                               const __hip_bfloat16* __restrict__ s_proj,
                                               float* __restrict__ out)
{
    int idx = blockIdx.x * 256 + threadIdx.x;   // (c, z)
    int c = idx / Zv;
    int z = idx - c * Zv;
    int b = z / Nv, n = z - b * Nv;
    float gamma = bnp[c], beta = bnp[Cv+c], mean = bnp[2*Cv+c], var = bnp[3*Cv+c];
    float scale = gamma / sqrtf(var + 1e-5f);
    size_t base = (size_t)idx * 4;
    float4 hv = *(const float4*)(h2 + base);
    float xi[4] = {hv.x, hv.y, hv.z, hv.w};
    ushort4 sp4 = *(const ushort4*)((const unsigned short*)s_proj + base);
    unsigned short* sps = (unsigned short*)&sp4;
    float mem = 0.f;
    #pragma unroll
    for (int t = 0; t < 4; ++t) {
        float bnv = (xi[t] - mean) * scale + beta;
        mem = mem + (bnv - mem) * 0.5f;
        float s = (mem > 1.0f) ? 1.0f : 0.0f;
        mem *= (1.0f - s);
        size_t oidx = ((size_t)(t * Bv + b) * Cv + c) * Nv + n;
        float sproj = sps[t] ? 1.0f : 0.0f;
        out[oidx] = x[oidx] + sproj + s;
    }
}

extern "C" void kernel_launch(void* const* d_in, const int* in_sizes, int n_in,
                              void* d_out, int out_size, void* d_ws, size_t ws_size,
                              hipStream_t stream)
{
    const float* x       = (const float*)d_in[0];
    const float* qkvp_w  = (const float*)d_in[1];
    const float* qkvp_bn = (const float*)d_in[2];
    const float* fc1_w   = (const float*)d_in[3];
    const float* fc1_b   = (const float*)d_in[4];
    const float* fc1_bn  = (const float*)d_in[5];
    const float* fc2_w   = (const float*)d_in[6];
    const float* fc2_b   = (const float*)d_in[7];
    const float* fc2_bn  = (const float*)d_in[8];

    float* out1 = (float*)d_out;                    // x_out fp32
    float* out2 = out1 + (size_t)TBv * Cv * Nv;     // v fp32

    const size_t S  = (size_t)Cv * Mv;
    const size_t S4 = S * 4;                        // bytes per slot
    if (ws_size < 4 * S4) return;

    char* wb = (char*)d_ws;
    float* xp            = (float*)wb;                       // @0: xp->x1, later h2
    float* ybuf          = (float*)(wb + S4);                // @1: q/k pre-BN, attn o
    __hip_bfloat16* qs   = (__hip_bfloat16*)(wb + 2*S4);     // @2.0 (bf16, 0.5)
    __hip_bfloat16* ks   = (__hip_bfloat16*)(wb + 2*S4 + S4/2); // @2.5
    __hip_bfloat16* vs   = (__hip_bfloat16*)(wb + 3*S4);     // @3.0
    float* pbuf          = (float*)(wb + 2*S4);              // @2.0-3.0 (q/k dead)
    __hip_bfloat16* s_pr = (__hip_bfloat16*)(wb + 3*S4 + S4/2); // @3.5
    __hip_bfloat16* H    = (__hip_bfloat16*)(wb + S4);       // @1.0-3.0 fc1 spikes
    float* h2            = (float*)wb;                       // @0 (x1 dead)

    k_transpose_in<<<(int)(S/256), 256, 0, stream>>>(x, xp);

    // q, k: 4x8 GEMM (bitwise r4 chain) + proven BN/LIF
    for (int br = 0; br < 2; ++br) {
        k_gemm4<0><<<dim3(196, 6), 256, 0, stream>>>(qkvp_w + (size_t)br*Cv*Cv, xp,
                                                     ybuf, Cv, Mv, Mv, nullptr, 0);
        __hip_bfloat16* sp = (br == 0) ? qs : ks;
        k_bnlif_spike<<<(int)(S/1024), 256, 0, stream>>>(ybuf, qkvp_bn + (size_t)br*4*Cv, sp);
    }
    // v: SSE2-SOP flavor (byte-identical)
    k_vsse2<<<dim3(392, 6), 256, 0, stream>>>(qkvp_w + (size_t)2*Cv*Cv, xp,
                                              qkvp_bn + (size_t)2*4*Cv, vs);

    k_attn<<<dim3(12, 128), 256, 0, stream>>>(qs, ks, vs, ybuf, out2);
    k_attnlif<<<(int)(S/1024), 256, 0, stream>>>(ybuf);

    k_gemm4<0><<<dim3(196, 6), 256, 0, stream>>>(qkvp_w + (size_t)3*Cv*Cv, ybuf,
                                                 pbuf, Cv, Mv, Mv, nullptr, 0);
    k_resid<<<(int)(S/1024), 256, 0, stream>>>(pbuf, qkvp_bn + (size_t)3*4*Cv, xp, s_pr);

    // fc1 full-M fused -> bf16 spikes @1.0-3.0
    k_fc1<<<dim3(196, 24), 256, 0, stream>>>(fc1_w, xp, fc1_b, fc1_bn, H);

    // fc2 full-M from bf16 spikes -> h2 @0
    k_gemm4<1><<<dim3(196, 6), 256, 0, stream>>>(fc2_w, H, h2,
                                                 HIDv, Mv, Mv, fc2_b, 0);

    k_final<<<(int)(S/1024), 256, 0, stream>>>(h2, fc2_bn, x, s_pr, out1);
}

// Round 17
// 1244.287 us; speedup vs baseline: 1.7427x; 1.0981x over previous
//
#include <hip/hip_runtime.h>
#include <hip/hip_bf16.h>

// Spiking transformer block (Spikformer SSA) on MI355X.
// Layout: [channel][m], m = (b*196+n)*4 + t (time innermost).
//
// CORRECTNESS CONTRACT (r11-r16 PASSED, absmax 0.0 bitwise):
//  - v branch: numpy SSE2-SOP einsum flavor (k_vsse2, byte-identical r12).
//  - out0 GEMMs: in-order ascending-k fp32 FMA chain per element, zero-init,
//    plain +bias at end (r4 flavor). BN/LIF epilogues: r7's exact explicit
//    __f*_rn sequence (r7-proven on q/k/proj/fc1/fc2). x1 = __fadd_rn(x, s).
//  - bf16 spike storage exact ({0,1}); retiling bitwise-safe.
// r13: no min-waves hints (AGPR spill). r16 diagnosis: LDS is shared by 4
// SIMDs -> 3 ds_read/kk makes every GEMM ~2.2x the FMA floor. Fix: wave-
// uniform W via readfirstlane -> W in SGPRs (s_load), only X in LDS (1 read/kk).

#define Cv 384
#define Nv 196
#define Mv 25088        // 128*196 columns
#define HIDv 1536
#define Bv 32
#define Zv 6272         // z = b*196+n
#define TBv 128

// ---- transpose: xp[c*Mv + (b*196+n)*4 + t] = x[((t*32+b)*384+c)*196+n] ----
__global__ __launch_bounds__(256) void k_transpose_in(const float* __restrict__ x,
                                                      float* __restrict__ xp)
{
    int idx = blockIdx.x * 256 + threadIdx.x;
    int c   = idx / Mv;
    int rem = idx - c * Mv;
    int z = rem >> 2, t = rem & 3;
    int b = z / Nv, n = z - b * Nv;
    xp[idx] = x[((size_t)(t * Bv + b) * Cv + c) * Nv + n];
}

// ---- W-uniform GEMM: 4 waves x 8 o-rows, lane = 4 m (one site), BK=8 -------
// Per-element chain bitwise == r4 flavor: acc = fmaf(W[o][k], X[k][m], acc),
// k ascending, zero-init. W reads are wave-uniform -> SGPR (s_load), no LDS.
// EPI=0: Y fp32 = acc + bias (r4).  EPI=1: r7 explicit BN/LIF -> bf16 spikes.
template<int XBF16, int SADD, int BIAS, int EPI>
__global__ __launch_bounds__(256) void k_gemm5(const float* __restrict__ W,
                                               const void* __restrict__ Xv,
                                               const __hip_bfloat16* __restrict__ Xs,
                                               const float* __restrict__ bias,
                                               const float* __restrict__ bnp,
                                               int bnC,
                                               void* __restrict__ Y,
                                               int K)
{
    __shared__ float sX[8][256];    // 8KB
    int tid  = threadIdx.x;
    int lane = tid & 63;
    int wid  = __builtin_amdgcn_readfirstlane(tid >> 6);   // wave-uniform
    int m0   = blockIdx.x * 256;
    int ob   = blockIdx.y * 32 + wid * 8;                  // scalar o-base
    int mL   = m0 + lane * 4;
    int sr   = tid >> 5;            // staging row 0..7
    int sc   = (tid & 31) * 8;      // staging col group

    float acc[8][4];
    #pragma unroll
    for (int i = 0; i < 8; ++i)
        #pragma unroll
        for (int j = 0; j < 4; ++j) acc[i][j] = 0.0f;

    for (int k0 = 0; k0 < K; k0 += 8) {
        float xf[8];
        if (XBF16) {
            const unsigned short* Xb = (const unsigned short*)Xv;
            uint4 u = *(const uint4*)(Xb + (size_t)(k0 + sr) * Mv + m0 + sc);
            unsigned uu[4] = {u.x, u.y, u.z, u.w};
            #pragma unroll
            for (int q = 0; q < 4; ++q) {
                xf[2*q]   = __uint_as_float((uu[q] & 0xFFFFu) << 16);
                xf[2*q+1] = __uint_as_float(uu[q] & 0xFFFF0000u);
            }
        } else {
            const float* Xf = (const float*)Xv;
            float4 xa = *(const float4*)(Xf + (size_t)(k0 + sr) * Mv + m0 + sc);
            float4 xb = *(const float4*)(Xf + (size_t)(k0 + sr) * Mv + m0 + sc + 4);
            xf[0]=xa.x; xf[1]=xa.y; xf[2]=xa.z; xf[3]=xa.w;
            xf[4]=xb.x; xf[5]=xb.y; xf[6]=xb.z; xf[7]=xb.w;
            if (SADD) {
                uint4 u = *(const uint4*)((const unsigned short*)Xs +
                                          (size_t)(k0 + sr) * Mv + m0 + sc);
                unsigned uu[4] = {u.x, u.y, u.z, u.w};
                #pragma unroll
                for (int q = 0; q < 4; ++q) {
                    xf[2*q]   = __fadd_rn(xf[2*q],   (uu[q] & 0xFFFFu)      ? 1.0f : 0.0f);
                    xf[2*q+1] = __fadd_rn(xf[2*q+1], (uu[q] & 0xFFFF0000u) ? 1.0f : 0.0f);
                }
            }
        }
        __syncthreads();
        *(float4*)&sX[sr][sc]     = *(float4*)&xf[0];
        *(float4*)&sX[sr][sc + 4] = *(float4*)&xf[4];
        __syncthreads();
        const float* Wb = W + (size_t)ob * K + k0;     // scalar base
        #pragma unroll
        for (int kk = 0; kk < 8; ++kk) {
            float4 xq = *(const float4*)&sX[kk][lane * 4];
            float xv[4] = {xq.x, xq.y, xq.z, xq.w};
            #pragma unroll
            for (int i = 0; i < 8; ++i) {
                float wv = Wb[(size_t)i * K + kk];      // scalar load (SGPR)
                #pragma unroll
                for (int j = 0; j < 4; ++j)
                    acc[i][j] = fmaf(wv, xv[j], acc[i][j]);
            }
        }
    }

    #pragma unroll
    for (int i = 0; i < 8; ++i) {
        int o = ob + i;
        if (EPI == 0) {         // fp32 out + plain bias (r4 flavor)
            float bb = BIAS ? bias[o] : 0.0f;
            float4 r;
            r.x = acc[i][0] + bb; r.y = acc[i][1] + bb;
            r.z = acc[i][2] + bb; r.w = acc[i][3] + bb;
            *(float4*)((float*)Y + (size_t)o * Mv + mL) = r;
        } else {                // r7 explicit BN/LIF -> bf16 spikes
            float inv = __fdiv_rn(1.0f, __fsqrt_rn(__fadd_rn(bnp[3*bnC + o], 1e-5f)));
            float scl = __fmul_rn(bnp[o], inv);
            float mu  = bnp[2*bnC + o];
            float be  = bnp[bnC + o];
            float mem = 0.0f;
            ushort4 pk;
            unsigned short* pks = (unsigned short*)&pk;
            #pragma unroll
            for (int j = 0; j < 4; ++j) {
                float val = acc[i][j];
                if (BIAS) val = __fadd_rn(val, bias[o]);
                float bn = __fadd_rn(__fmul_rn(__fsub_rn(val, mu), scl), be);
                mem = __fadd_rn(mem, __fmul_rn(__fsub_rn(bn, mem), 0.5f));
                int s = (mem > 1.0f);
                mem = s ? 0.0f : mem;
                pks[j] = s ? 0x3F80 : 0;
            }
            *(ushort4*)((unsigned short*)Y + (size_t)o * Mv + mL) = pk;
        }
    }
}

// ---- V branch: SSE2-SOP GEMM (byte-identical r12/r14/r15/r16 kernel) -------
__global__ __launch_bounds__(256) void k_vsse2(const float* __restrict__ W,
                                               const float* __restrict__ X,
                                               const float* __restrict__ bnp,
                                               __hip_bfloat16* __restrict__ Y)
{
    __shared__ float sW[32][68];
    __shared__ float sX[32][64];
    int m0 = blockIdx.x * 64;
    int o0 = blockIdx.y * 64;
    int tid = threadIdx.x;
    int to = tid >> 4, tm = tid & 15;

    float acc[4][4][4];
    #pragma unroll
    for (int s = 0; s < 4; ++s)
        #pragma unroll
        for (int op = 0; op < 4; ++op)
            #pragma unroll
            for (int e = 0; e < 4; ++e) acc[s][op][e] = 0.0f;

    int wq_o = tid >> 3, wq_c = tid & 7;
    int xs_r = tid >> 3, xs_c = (tid & 7) * 8;

    for (int blk = 0; blk < 12; ++blk) {
        int k0 = blk * 32;
        __syncthreads();
        {
            float4 w4 = *(const float4*)(W + (size_t)(o0 + wq_o) * Cv + k0 + wq_c*4);
            sW[wq_c*4+0][wq_o] = w4.x;
            sW[wq_c*4+1][wq_o] = w4.y;
            sW[wq_c*4+2][wq_o] = w4.z;
            sW[wq_c*4+3][wq_o] = w4.w;
            float4 w5 = *(const float4*)(W + (size_t)(o0 + 32 + wq_o) * Cv + k0 + wq_c*4);
            sW[wq_c*4+0][32 + wq_o] = w5.x;
            sW[wq_c*4+1][32 + wq_o] = w5.y;
            sW[wq_c*4+2][32 + wq_o] = w5.z;
            sW[wq_c*4+3][32 + wq_o] = w5.w;
        }
        {
            const float* Xp = X + (size_t)(k0 + xs_r) * Mv + m0 + xs_c;
            *(float4*)&sX[xs_r][xs_c]     = *(const float4*)(Xp);
            *(float4*)&sX[xs_r][xs_c + 4] = *(const float4*)(Xp + 4);
        }
        __syncthreads();
        #pragma unroll
        for (int j = 0; j < 8; ++j) {
            #pragma unroll
            for (int s = 0; s < 4; ++s) {
                int kk = j * 4 + s;
                float4 w4 = *(const float4*)&sW[kk][to*4];
                float4 x4 = *(const float4*)&sX[kk][tm*4];
                float wv[4] = {w4.x, w4.y, w4.z, w4.w};
                float xv[4] = {x4.x, x4.y, x4.z, x4.w};
                #pragma unroll
                for (int op = 0; op < 4; ++op)
                    #pragma unroll
                    for (int e = 0; e < 4; ++e)
                        acc[s][op][e] = __fadd_rn(acc[s][op][e],
                                                  __fmul_rn(wv[op], xv[e]));
            }
        }
    }

    #pragma unroll
    for (int op = 0; op < 4; ++op) {
        int o = o0 + to*4 + op;
        float inv = __fdiv_rn(1.0f, __fsqrt_rn(__fadd_rn(bnp[3*Cv + o], 1e-5f)));
        float sc  = __fmul_rn(bnp[o], inv);
        float mu  = bnp[2*Cv + o];
        float be  = bnp[Cv + o];
        float mem = 0.0f;
        ushort4 pk;
        unsigned short* pks = (unsigned short*)&pk;
        #pragma unroll
        for (int e = 0; e < 4; ++e) {
            float tot = __fadd_rn(__fadd_rn(acc[0][op][e], acc[2][op][e]),
                                  __fadd_rn(acc[1][op][e], acc[3][op][e]));
            float bn = __fadd_rn(__fmul_rn(__fsub_rn(tot, mu), sc), be);
            mem = __fadd_rn(mem, __fmul_rn(__fsub_rn(bn, mem), 0.5f));
            int s = (mem > 1.0f);
            mem = s ? 0.0f : mem;
            pks[e] = s ? 0x3F80 : 0;
        }
        *(ushort4*)((unsigned short*)Y + (size_t)o * Mv + m0 + tm * 4) = pk;
    }
}

// ---- attention per (h, tbl): popcount QK^T, exact fp32 PV ------------------
__global__ __launch_bounds__(256) void k_attn(const __hip_bfloat16* __restrict__ qs,
                                              const __hip_bfloat16* __restrict__ ks,
                                              const __hip_bfloat16* __restrict__ vs,
                                              float* __restrict__ o_chan,
                                              float* __restrict__ v_out)
{
    int h = blockIdx.x, tbl = blockIdx.y;
    int t = tbl >> 5, b = tbl & 31;
    int tid = threadIdx.x;
    __shared__ unsigned kmask[196];
    __shared__ float vf[196][36];
    size_t chb  = (size_t)h * 32 * Mv;
    size_t colb = (size_t)b * Nv * 4 + t;

    for (int e = tid; e < Nv * 32; e += 256) {
        int dd = e / Nv, n = e - dd * Nv;
        vf[n][dd] = __bfloat162float(vs[chb + (size_t)dd * Mv + colb + (size_t)n * 4]);
    }
    unsigned qm = 0;
    if (tid < Nv) {
        unsigned km = 0;
        #pragma unroll
        for (int dd = 0; dd < 32; ++dd) {
            size_t off = chb + (size_t)dd * Mv + colb + (size_t)tid * 4;
            km |= (__bfloat162float(ks[off]) > 0.5f ? 1u : 0u) << dd;
            qm |= (__bfloat162float(qs[off]) > 0.5f ? 1u : 0u) << dd;
        }
        kmask[tid] = km;
    }
    __syncthreads();
    for (int e = tid; e < Nv * 32; e += 256) {
        int n = e >> 5, dd = e & 31;
        v_out[((size_t)(tbl * 12 + h) * Nv + n) * 32 + dd] = vf[n][dd];
    }
    if (tid < Nv) {
        float acc[32] = {};
        for (int nk = 0; nk < Nv; ++nk) {
            float a = (float)__popc(qm & kmask[nk]) * 0.125f;
            #pragma unroll
            for (int dd = 0; dd < 32; ++dd) acc[dd] += a * vf[nk][dd];
        }
        #pragma unroll
        for (int dd = 0; dd < 32; ++dd)
            o_chan[chb + (size_t)dd * Mv + colb + (size_t)tid * 4] = acc[dd];
    }
}

// ---- attn LIF (thr=0.5): exact (dyadic grid) -------------------------------
__global__ __launch_bounds__(256) void k_attnlif(float* __restrict__ o)
{
    int idx = blockIdx.x * 256 + threadIdx.x;
    size_t base = (size_t)idx * 4;
    float4 v = *(const float4*)(o + base);
    float xi[4] = {v.x, v.y, v.z, v.w};
    float s4[4];
    float mem = 0.f;
    #pragma unroll
    for (int t = 0; t < 4; ++t) {
        mem = mem + (xi[t] - mem) * 0.5f;
        s4[t] = (mem > 0.5f) ? 1.0f : 0.0f;
        mem *= (1.0f - s4[t]);
    }
    float4 r; r.x = s4[0]; r.y = s4[1]; r.z = s4[2]; r.w = s4[3];
    *(float4*)(o + base) = r;
}

// ---- fc2 BN+LIF + out = x + s_proj + s_fc2 (byte-identical r16) ------------
__global__ __launch_bounds__(256) void k_final(const float* __restrict__ h2,
                                               const float* __restrict__ bnp,
                                               const float* __restrict__ x,
                                               const __hip_bfloat16* __restrict__ s_proj,
                                               float* __restrict__ out)
{
    int idx = blockIdx.x * 256 + threadIdx.x;   // (c, z)
    int c = idx / Zv;
    int z = idx - c * Zv;
    int b = z / Nv, n = z - b * Nv;
    float gamma = bnp[c], beta = bnp[Cv+c], mean = bnp[2*Cv+c], var = bnp[3*Cv+c];
    float scale = gamma / sqrtf(var + 1e-5f);
    size_t base = (size_t)idx * 4;
    float4 hv = *(const float4*)(h2 + base);
    float xi[4] = {hv.x, hv.y, hv.z, hv.w};
    ushort4 sp4 = *(const ushort4*)((const unsigned short*)s_proj + base);
    unsigned short* sps = (unsigned short*)&sp4;
    float mem = 0.f;
    #pragma unroll
    for (int t = 0; t < 4; ++t) {
        float bnv = (xi[t] - mean) * scale + beta;
        mem = mem + (bnv - mem) * 0.5f;
        float s = (mem > 1.0f) ? 1.0f : 0.0f;
        mem *= (1.0f - s);
        size_t oidx = ((size_t)(t * Bv + b) * Cv + c) * Nv + n;
        float sproj = sps[t] ? 1.0f : 0.0f;
        out[oidx] = x[oidx] + sproj + s;
    }
}

extern "C" void kernel_launch(void* const* d_in, const int* in_sizes, int n_in,
                              void* d_out, int out_size, void* d_ws, size_t ws_size,
                              hipStream_t stream)
{
    const float* x       = (const float*)d_in[0];
    const float* qkvp_w  = (const float*)d_in[1];
    const float* qkvp_bn = (const float*)d_in[2];
    const float* fc1_w   = (const float*)d_in[3];
    const float* fc1_b   = (const float*)d_in[4];
    const float* fc1_bn  = (const float*)d_in[5];
    const float* fc2_w   = (const float*)d_in[6];
    const float* fc2_b   = (const float*)d_in[7];
    const float* fc2_bn  = (const float*)d_in[8];

    float* out1 = (float*)d_out;                    // x_out fp32
    float* out2 = out1 + (size_t)TBv * Cv * Nv;     // v fp32

    const size_t S  = (size_t)Cv * Mv;
    const size_t S4 = S * 4;
    if (ws_size < 4 * S4) return;

    char* wb = (char*)d_ws;
    float* xp            = (float*)wb;                          // @0 (until fc1)
    float* obuf          = (float*)(wb + S4);                   // @1: attn o
    __hip_bfloat16* qs   = (__hip_bfloat16*)(wb + 2*S4);        // @2.0
    __hip_bfloat16* ks   = (__hip_bfloat16*)(wb + 2*S4 + S4/2); // @2.5
    __hip_bfloat16* vs   = (__hip_bfloat16*)(wb + 3*S4);        // @3.0
    __hip_bfloat16* s_pr = (__hip_bfloat16*)(wb + 3*S4 + S4/2); // @3.5
    __hip_bfloat16* H    = (__hip_bfloat16*)(wb + S4);          // @1.0-3.0 fc1 spikes
    float* h2            = (float*)wb;                          // @0 (xp dead)

    k_transpose_in<<<(int)(S/256), 256, 0, stream>>>(x, xp);

    // q, k: W-uniform GEMM + fused r7 BN/LIF -> bf16 spikes
    k_gemm5<0,0,0,1><<<dim3(98, 12), 256, 0, stream>>>(
        qkvp_w, xp, nullptr, nullptr, qkvp_bn, Cv, qs, Cv);
    k_gemm5<0,0,0,1><<<dim3(98, 12), 256, 0, stream>>>(
        qkvp_w + (size_t)Cv*Cv, xp, nullptr, nullptr, qkvp_bn + 4*Cv, Cv, ks, Cv);
    // v: SSE2-SOP flavor (byte-identical)
    k_vsse2<<<dim3(392, 6), 256, 0, stream>>>(qkvp_w + (size_t)2*Cv*Cv, xp,
                                              qkvp_bn + (size_t)2*4*Cv, vs);

    k_attn<<<dim3(12, 128), 256, 0, stream>>>(qs, ks, vs, obuf, out2);
    k_attnlif<<<(int)(S/1024), 256, 0, stream>>>(obuf);

    // proj: GEMM + fused r7 BN/LIF -> s_proj
    k_gemm5<0,0,0,1><<<dim3(98, 12), 256, 0, stream>>>(
        qkvp_w + (size_t)3*Cv*Cv, obuf, nullptr, nullptr, qkvp_bn + 3*4*Cv, Cv, s_pr, Cv);

    // fc1: GEMM over (xp + s_proj) + bias + BN/LIF -> H spikes
    k_gemm5<0,1,1,1><<<dim3(98, 48), 256, 0, stream>>>(
        fc1_w, xp, s_pr, fc1_b, fc1_bn, HIDv, H, Cv);

    // fc2: GEMM from bf16 spikes + bias -> h2 fp32
    k_gemm5<1,0,1,0><<<dim3(98, 12), 256, 0, stream>>>(
        fc2_w, H, nullptr, fc2_b, nullptr, 0, h2, HIDv);

    k_final<<<(int)(S/1024), 256, 0, stream>>>(h2, fc2_bn, x, s_pr, out1);
}

// Round 18
// 1191.993 us; speedup vs baseline: 1.8191x; 1.0439x over previous
//
#include <hip/hip_runtime.h>
#include <hip/hip_bf16.h>

// Spiking transformer block (Spikformer SSA) on MI355X.
// Layout: [channel][m], m = (b*196+n)*4 + t (time innermost).
//
// CORRECTNESS CONTRACT (r11-r17 PASSED, absmax 0.0 bitwise):
//  - v branch: numpy SSE2-SOP einsum flavor (k_vsse2 body byte-identical r12;
//    r18 changes only its block->tile index mapping, bitwise-safe).
//  - out0 GEMMs: in-order ascending-k fp32 FMA chain per element, zero-init;
//    r7 explicit __f*_rn BN/LIF epilogues; x1 = __fadd_rn(x, s) at stage.
//  - bf16 spike storage exact ({0,1}); retiling/swizzle bitwise-safe.
// r13: no min-waves hints (AGPR spill). r16: W wave-uniform -> SGPR, X-only
// LDS. r17 diagnosis: (a) 1.3GB X re-fetch/dispatch (o-blocks for one m-tile
// scattered across XCDs) -> bijective XCD swizzle groups same-m-tile blocks
// per XCD (W + X panel stay L2-resident); (b) staging writes at 32B lane
// stride were 8-way bank conflicts -> consecutive-16B staging.

#define Cv 384
#define Nv 196
#define Mv 25088        // 128*196 columns
#define HIDv 1536
#define Bv 32
#define Zv 6272         // z = b*196+n
#define TBv 128

// ---- transpose: xp[c*Mv + (b*196+n)*4 + t] = x[((t*32+b)*384+c)*196+n] ----
__global__ __launch_bounds__(256) void k_transpose_in(const float* __restrict__ x,
                                                      float* __restrict__ xp)
{
    int idx = blockIdx.x * 256 + threadIdx.x;
    int c   = idx / Mv;
    int rem = idx - c * Mv;
    int z = rem >> 2, t = rem & 3;
    int b = z / Nv, n = z - b * Nv;
    xp[idx] = x[((size_t)(t * Bv + b) * Cv + c) * Nv + n];
}

// ---- W-uniform GEMM: 4 waves x 8 o-rows, lane = 4 m, BK=8, XCD-swizzled ----
// Per-element chain bitwise == r4 flavor: acc = fmaf(W[o][k], X[k][m], acc),
// k ascending, zero-init. W wave-uniform -> SGPR. 1D grid, bijective swizzle:
// idp = (id&7)*(nwg/8) + (id>>3); m_tile = idp/NO, o_tile = idp%NO.
template<int XBF16, int SADD, int BIAS, int EPI>
__global__ __launch_bounds__(256) void k_gemm5(const float* __restrict__ W,
                                               const void* __restrict__ Xv,
                                               const __hip_bfloat16* __restrict__ Xs,
                                               const float* __restrict__ bias,
                                               const float* __restrict__ bnp,
                                               int bnC,
                                               void* __restrict__ Y,
                                               int K, int NO)
{
    __shared__ float sX[8][256];    // 8KB
    int id    = blockIdx.x;
    int chunk = gridDim.x >> 3;                            // nwg % 8 == 0
    int idp   = (id & 7) * chunk + (id >> 3);
    int m0    = (idp / NO) * 256;
    int obt   = idp % NO;
    int tid  = threadIdx.x;
    int lane = tid & 63;
    int wid  = __builtin_amdgcn_readfirstlane(tid >> 6);   // wave-uniform
    int ob   = obt * 32 + wid * 8;                         // scalar o-base
    int mL   = m0 + lane * 4;
    int r1   = tid >> 6;            // staging rows r1, r1+4
    int c1   = (tid & 63) * 4;      // consecutive 16B per lane: conflict-free

    float acc[8][4];
    #pragma unroll
    for (int i = 0; i < 8; ++i)
        #pragma unroll
        for (int j = 0; j < 4; ++j) acc[i][j] = 0.0f;

    for (int k0 = 0; k0 < K; k0 += 8) {
        float xfa[4], xfb[4];
        if (XBF16) {
            const unsigned short* Xb = (const unsigned short*)Xv;
            uint2 ua = *(const uint2*)(Xb + (size_t)(k0 + r1) * Mv + m0 + c1);
            uint2 ub = *(const uint2*)(Xb + (size_t)(k0 + r1 + 4) * Mv + m0 + c1);
            xfa[0] = __uint_as_float((ua.x & 0xFFFFu) << 16);
            xfa[1] = __uint_as_float(ua.x & 0xFFFF0000u);
            xfa[2] = __uint_as_float((ua.y & 0xFFFFu) << 16);
            xfa[3] = __uint_as_float(ua.y & 0xFFFF0000u);
            xfb[0] = __uint_as_float((ub.x & 0xFFFFu) << 16);
            xfb[1] = __uint_as_float(ub.x & 0xFFFF0000u);
            xfb[2] = __uint_as_float((ub.y & 0xFFFFu) << 16);
            xfb[3] = __uint_as_float(ub.y & 0xFFFF0000u);
        } else {
            const float* Xf = (const float*)Xv;
            float4 xa = *(const float4*)(Xf + (size_t)(k0 + r1) * Mv + m0 + c1);
            float4 xb = *(const float4*)(Xf + (size_t)(k0 + r1 + 4) * Mv + m0 + c1);
            xfa[0]=xa.x; xfa[1]=xa.y; xfa[2]=xa.z; xfa[3]=xa.w;
            xfb[0]=xb.x; xfb[1]=xb.y; xfb[2]=xb.z; xfb[3]=xb.w;
            if (SADD) {
                const unsigned short* Sb = (const unsigned short*)Xs;
                uint2 ua = *(const uint2*)(Sb + (size_t)(k0 + r1) * Mv + m0 + c1);
                uint2 ub = *(const uint2*)(Sb + (size_t)(k0 + r1 + 4) * Mv + m0 + c1);
                xfa[0] = __fadd_rn(xfa[0], (ua.x & 0xFFFFu)      ? 1.0f : 0.0f);
                xfa[1] = __fadd_rn(xfa[1], (ua.x & 0xFFFF0000u) ? 1.0f : 0.0f);
                xfa[2] = __fadd_rn(xfa[2], (ua.y & 0xFFFFu)      ? 1.0f : 0.0f);
                xfa[3] = __fadd_rn(xfa[3], (ua.y & 0xFFFF0000u) ? 1.0f : 0.0f);
                xfb[0] = __fadd_rn(xfb[0], (ub.x & 0xFFFFu)      ? 1.0f : 0.0f);
                xfb[1] = __fadd_rn(xfb[1], (ub.x & 0xFFFF0000u) ? 1.0f : 0.0f);
                xfb[2] = __fadd_rn(xfb[2], (ub.y & 0xFFFFu)      ? 1.0f : 0.0f);
                xfb[3] = __fadd_rn(xfb[3], (ub.y & 0xFFFF0000u) ? 1.0f : 0.0f);
            }
        }
        __syncthreads();
        *(float4*)&sX[r1][c1]     = *(float4*)&xfa[0];
        *(float4*)&sX[r1 + 4][c1] = *(float4*)&xfb[0];
        __syncthreads();
        const float* Wb = W + (size_t)ob * K + k0;     // scalar base
        #pragma unroll
        for (int kk = 0; kk < 8; ++kk) {
            float4 xq = *(const float4*)&sX[kk][lane * 4];
            float xv[4] = {xq.x, xq.y, xq.z, xq.w};
            #pragma unroll
            for (int i = 0; i < 8; ++i) {
                float wv = Wb[(size_t)i * K + kk];      // scalar load (SGPR)
                #pragma unroll
                for (int j = 0; j < 4; ++j)
                    acc[i][j] = fmaf(wv, xv[j], acc[i][j]);
            }
        }
    }

    #pragma unroll
    for (int i = 0; i < 8; ++i) {
        int o = ob + i;
        if (EPI == 0) {         // fp32 out + plain bias (r4 flavor)
            float bb = BIAS ? bias[o] : 0.0f;
            float4 r;
            r.x = acc[i][0] + bb; r.y = acc[i][1] + bb;
            r.z = acc[i][2] + bb; r.w = acc[i][3] + bb;
            *(float4*)((float*)Y + (size_t)o * Mv + mL) = r;
        } else {                // r7 explicit BN/LIF -> bf16 spikes
            float inv = __fdiv_rn(1.0f, __fsqrt_rn(__fadd_rn(bnp[3*bnC + o], 1e-5f)));
            float scl = __fmul_rn(bnp[o], inv);
            float mu  = bnp[2*bnC + o];
            float be  = bnp[bnC + o];
            float mem = 0.0f;
            ushort4 pk;
            unsigned short* pks = (unsigned short*)&pk;
            #pragma unroll
            for (int j = 0; j < 4; ++j) {
                float val = acc[i][j];
                if (BIAS) val = __fadd_rn(val, bias[o]);
                float bn = __fadd_rn(__fmul_rn(__fsub_rn(val, mu), scl), be);
                mem = __fadd_rn(mem, __fmul_rn(__fsub_rn(bn, mem), 0.5f));
                int s = (mem > 1.0f);
                mem = s ? 0.0f : mem;
                pks[j] = s ? 0x3F80 : 0;
            }
            *(ushort4*)((unsigned short*)Y + (size_t)o * Mv + mL) = pk;
        }
    }
}

// ---- V branch: SSE2-SOP GEMM (r12 body; XCD-swizzled 1D grid, NO=6) --------
__global__ __launch_bounds__(256) void k_vsse2(const float* __restrict__ W,
                                               const float* __restrict__ X,
                                               const float* __restrict__ bnp,
                                               __hip_bfloat16* __restrict__ Y)
{
    __shared__ float sW[32][68];
    __shared__ float sX[32][64];
    int id    = blockIdx.x;
    int chunk = gridDim.x >> 3;
    int idp   = (id & 7) * chunk + (id >> 3);
    int m0    = (idp / 6) * 64;
    int o0    = (idp % 6) * 64;
    int tid = threadIdx.x;
    int to = tid >> 4, tm = tid & 15;

    float acc[4][4][4];
    #pragma unroll
    for (int s = 0; s < 4; ++s)
        #pragma unroll
        for (int op = 0; op < 4; ++op)
            #pragma unroll
            for (int e = 0; e < 4; ++e) acc[s][op][e] = 0.0f;

    int wq_o = tid >> 3, wq_c = tid & 7;
    int xs_r = tid >> 3, xs_c = (tid & 7) * 8;

    for (int blk = 0; blk < 12; ++blk) {
        int k0 = blk * 32;
        __syncthreads();
        {
            float4 w4 = *(const float4*)(W + (size_t)(o0 + wq_o) * Cv + k0 + wq_c*4);
            sW[wq_c*4+0][wq_o] = w4.x;
            sW[wq_c*4+1][wq_o] = w4.y;
            sW[wq_c*4+2][wq_o] = w4.z;
            sW[wq_c*4+3][wq_o] = w4.w;
            float4 w5 = *(const float4*)(W + (size_t)(o0 + 32 + wq_o) * Cv + k0 + wq_c*4);
            sW[wq_c*4+0][32 + wq_o] = w5.x;
            sW[wq_c*4+1][32 + wq_o] = w5.y;
            sW[wq_c*4+2][32 + wq_o] = w5.z;
            sW[wq_c*4+3][32 + wq_o] = w5.w;
        }
        {
            const float* Xp = X + (size_t)(k0 + xs_r) * Mv + m0 + xs_c;
            *(float4*)&sX[xs_r][xs_c]     = *(const float4*)(Xp);
            *(float4*)&sX[xs_r][xs_c + 4] = *(const float4*)(Xp + 4);
        }
        __syncthreads();
        #pragma unroll
        for (int j = 0; j < 8; ++j) {
            #pragma unroll
            for (int s = 0; s < 4; ++s) {
                int kk = j * 4 + s;
                float4 w4 = *(const float4*)&sW[kk][to*4];
                float4 x4 = *(const float4*)&sX[kk][tm*4];
                float wv[4] = {w4.x, w4.y, w4.z, w4.w};
                float xv[4] = {x4.x, x4.y, x4.z, x4.w};
                #pragma unroll
                for (int op = 0; op < 4; ++op)
                    #pragma unroll
                    for (int e = 0; e < 4; ++e)
                        acc[s][op][e] = __fadd_rn(acc[s][op][e],
                                                  __fmul_rn(wv[op], xv[e]));
            }
        }
    }

    #pragma unroll
    for (int op = 0; op < 4; ++op) {
        int o = o0 + to*4 + op;
        float inv = __fdiv_rn(1.0f, __fsqrt_rn(__fadd_rn(bnp[3*Cv + o], 1e-5f)));
        float sc  = __fmul_rn(bnp[o], inv);
        float mu  = bnp[2*Cv + o];
        float be  = bnp[Cv + o];
        float mem = 0.0f;
        ushort4 pk;
        unsigned short* pks = (unsigned short*)&pk;
        #pragma unroll
        for (int e = 0; e < 4; ++e) {
            float tot = __fadd_rn(__fadd_rn(acc[0][op][e], acc[2][op][e]),
                                  __fadd_rn(acc[1][op][e], acc[3][op][e]));
            float bn = __fadd_rn(__fmul_rn(__fsub_rn(tot, mu), sc), be);
            mem = __fadd_rn(mem, __fmul_rn(__fsub_rn(bn, mem), 0.5f));
            int s = (mem > 1.0f);
            mem = s ? 0.0f : mem;
            pks[e] = s ? 0x3F80 : 0;
        }
        *(ushort4*)((unsigned short*)Y + (size_t)o * Mv + m0 + tm * 4) = pk;
    }
}

// ---- attention per (h, tbl): popcount QK^T, exact fp32 PV ------------------
__global__ __launch_bounds__(256) void k_attn(const __hip_bfloat16* __restrict__ qs,
                                              const __hip_bfloat16* __restrict__ ks,
                                              const __hip_bfloat16* __restrict__ vs,
                                              float* __restrict__ o_chan,
                                              float* __restrict__ v_out)
{
    int h = blockIdx.x, tbl = blockIdx.y;
    int t = tbl >> 5, b = tbl & 31;
    int tid = threadIdx.x;
    __shared__ unsigned kmask[196];
    __shared__ float vf[196][36];
    size_t chb  = (size_t)h * 32 * Mv;
    size_t colb = (size_t)b * Nv * 4 + t;

    for (int e = tid; e < Nv * 32; e += 256) {
        int dd = e / Nv, n = e - dd * Nv;
        vf[n][dd] = __bfloat162float(vs[chb + (size_t)dd * Mv + colb + (size_t)n * 4]);
    }
    unsigned qm = 0;
    if (tid < Nv) {
        unsigned km = 0;
        #pragma unroll
        for (int dd = 0; dd < 32; ++dd) {
            size_t off = chb + (size_t)dd * Mv + colb + (size_t)tid * 4;
            km |= (__bfloat162float(ks[off]) > 0.5f ? 1u : 0u) << dd;
            qm |= (__bfloat162float(qs[off]) > 0.5f ? 1u : 0u) << dd;
        }
        kmask[tid] = km;
    }
    __syncthreads();
    for (int e = tid; e < Nv * 32; e += 256) {
        int n = e >> 5, dd = e & 31;
        v_out[((size_t)(tbl * 12 + h) * Nv + n) * 32 + dd] = vf[n][dd];
    }
    if (tid < Nv) {
        float acc[32] = {};
        for (int nk = 0; nk < Nv; ++nk) {
            float a = (float)__popc(qm & kmask[nk]) * 0.125f;
            #pragma unroll
            for (int dd = 0; dd < 32; ++dd) acc[dd] += a * vf[nk][dd];
        }
        #pragma unroll
        for (int dd = 0; dd < 32; ++dd)
            o_chan[chb + (size_t)dd * Mv + colb + (size_t)tid * 4] = acc[dd];
    }
}

// ---- attn LIF (thr=0.5): exact (dyadic grid) -------------------------------
__global__ __launch_bounds__(256) void k_attnlif(float* __restrict__ o)
{
    int idx = blockIdx.x * 256 + threadIdx.x;
    size_t base = (size_t)idx * 4;
    float4 v = *(const float4*)(o + base);
    float xi[4] = {v.x, v.y, v.z, v.w};
    float s4[4];
    float mem = 0.f;
    #pragma unroll
    for (int t = 0; t < 4; ++t) {
        mem = mem + (xi[t] - mem) * 0.5f;
        s4[t] = (mem > 0.5f) ? 1.0f : 0.0f;
        mem *= (1.0f - s4[t]);
    }
    float4 r; r.x = s4[0]; r.y = s4[1]; r.z = s4[2]; r.w = s4[3];
    *(float4*)(o + base) = r;
}

// ---- fc2 BN+LIF + out = x + s_proj + s_fc2 (byte-identical r16) ------------
__global__ __launch_bounds__(256) void k_final(const float* __restrict__ h2,
                                               const float* __restrict__ bnp,
                                               const float* __restrict__ x,
                                               const __hip_bfloat16* __restrict__ s_proj,
                                               float* __restrict__ out)
{
    int idx = blockIdx.x * 256 + threadIdx.x;   // (c, z)
    int c = idx / Zv;
    int z = idx - c * Zv;
    int b = z / Nv, n = z - b * Nv;
    float gamma = bnp[c], beta = bnp[Cv+c], mean = bnp[2*Cv+c], var = bnp[3*Cv+c];
    float scale = gamma / sqrtf(var + 1e-5f);
    size_t base = (size_t)idx * 4;
    float4 hv = *(const float4*)(h2 + base);
    float xi[4] = {hv.x, hv.y, hv.z, hv.w};
    ushort4 sp4 = *(const ushort4*)((const unsigned short*)s_proj + base);
    unsigned short* sps = (unsigned short*)&sp4;
    float mem = 0.f;
    #pragma unroll
    for (int t = 0; t < 4; ++t) {
        float bnv = (xi[t] - mean) * scale + beta;
        mem = mem + (bnv - mem) * 0.5f;
        float s = (mem > 1.0f) ? 1.0f : 0.0f;
        mem *= (1.0f - s);
        size_t oidx = ((size_t)(t * Bv + b) * Cv + c) * Nv + n;
        float sproj = sps[t] ? 1.0f : 0.0f;
        out[oidx] = x[oidx] + sproj + s;
    }
}

extern "C" void kernel_launch(void* const* d_in, const int* in_sizes, int n_in,
                              void* d_out, int out_size, void* d_ws, size_t ws_size,
                              hipStream_t stream)
{
    const float* x       = (const float*)d_in[0];
    const float* qkvp_w  = (const float*)d_in[1];
    const float* qkvp_bn = (const float*)d_in[2];
    const float* fc1_w   = (const float*)d_in[3];
    const float* fc1_b   = (const float*)d_in[4];
    const float* fc1_bn  = (const float*)d_in[5];
    const float* fc2_w   = (const float*)d_in[6];
    const float* fc2_b   = (const float*)d_in[7];
    const float* fc2_bn  = (const float*)d_in[8];

    float* out1 = (float*)d_out;                    // x_out fp32
    float* out2 = out1 + (size_t)TBv * Cv * Nv;     // v fp32

    const size_t S  = (size_t)Cv * Mv;
    const size_t S4 = S * 4;
    if (ws_size < 4 * S4) return;

    char* wb = (char*)d_ws;
    float* xp            = (float*)wb;                          // @0 (until fc1)
    float* obuf          = (float*)(wb + S4);                   // @1: attn o
    __hip_bfloat16* qs   = (__hip_bfloat16*)(wb + 2*S4);        // @2.0
    __hip_bfloat16* ks   = (__hip_bfloat16*)(wb + 2*S4 + S4/2); // @2.5
    __hip_bfloat16* vs   = (__hip_bfloat16*)(wb + 3*S4);        // @3.0
    __hip_bfloat16* s_pr = (__hip_bfloat16*)(wb + 3*S4 + S4/2); // @3.5
    __hip_bfloat16* H    = (__hip_bfloat16*)(wb + S4);          // @1.0-3.0 fc1 spikes
    float* h2            = (float*)wb;                          // @0 (xp dead)

    k_transpose_in<<<(int)(S/256), 256, 0, stream>>>(x, xp);

    // q, k: W-uniform GEMM + fused r7 BN/LIF -> bf16 spikes  (nwg=1176, NO=12)
    k_gemm5<0,0,0,1><<<1176, 256, 0, stream>>>(
        qkvp_w, xp, nullptr, nullptr, qkvp_bn, Cv, qs, Cv, 12);
    k_gemm5<0,0,0,1><<<1176, 256, 0, stream>>>(
        qkvp_w + (size_t)Cv*Cv, xp, nullptr, nullptr, qkvp_bn + 4*Cv, Cv, ks, Cv, 12);
    // v: SSE2-SOP flavor (swizzled grid, nwg=2352, NO=6)
    k_vsse2<<<2352, 256, 0, stream>>>(qkvp_w + (size_t)2*Cv*Cv, xp,
                                      qkvp_bn + (size_t)2*4*Cv, vs);

    k_attn<<<dim3(12, 128), 256, 0, stream>>>(qs, ks, vs, obuf, out2);
    k_attnlif<<<(int)(S/1024), 256, 0, stream>>>(obuf);

    // proj: GEMM + fused r7 BN/LIF -> s_proj
    k_gemm5<0,0,0,1><<<1176, 256, 0, stream>>>(
        qkvp_w + (size_t)3*Cv*Cv, obuf, nullptr, nullptr, qkvp_bn + 3*4*Cv, Cv, s_pr, Cv, 12);

    // fc1: GEMM over (xp + s_proj) + bias + BN/LIF -> H spikes  (nwg=4704, NO=48)
    k_gemm5<0,1,1,1><<<4704, 256, 0, stream>>>(
        fc1_w, xp, s_pr, fc1_b, fc1_bn, HIDv, H, Cv, 48);

    // fc2: GEMM from bf16 spikes + bias -> h2 fp32  (nwg=1176, NO=12)
    k_gemm5<1,0,1,0><<<1176, 256, 0, stream>>>(
        fc2_w, H, nullptr, fc2_b, nullptr, 0, h2, HIDv, 12);

    k_final<<<(int)(S/1024), 256, 0, stream>>>(h2, fc2_bn, x, s_pr, out1);
}